// Round 3
// baseline (5001.226 us; speedup 1.0000x reference)
//
#include <hip/hip_runtime.h>
#include <hip/hip_bf16.h>
#include <math.h>

#define B_ 8
#define N_TOK 4096
#define C_ 768
#define H_ 12
#define HD_ 64
#define M_ 266
#define TC_ 2304
#define BH_ 96
#define ROWS_ 32768

#define DN 0.35355339059327373f      // 1/sqrt(sqrt(64))
#define RATIO 0.06131393394849658f   // 1/sqrt(266)
#define FEPS 1e-4f
#define NEG_INF -3.0e38f

__device__ __forceinline__ float bf2f(unsigned short u) {
  return __uint_as_float(((unsigned int)u) << 16);
}
__device__ __forceinline__ unsigned short f2bf(float f) {
  unsigned int x = __float_as_uint(f);
  unsigned int r = (x + 0x7fffu + ((x >> 16) & 1u)) >> 16;
  return (unsigned short)r;
}

// ---------------- K1/K7: SGEMM 128x128x16, 8x8 per thread ----------------
// A_BF16: A is bf16 (else f32). C_BF16: C stored bf16 (else f32 + bias).
template <int A_BF16, int C_BF16>
__global__ __launch_bounds__(256) void sgemm128(
    const void* __restrict__ Aptr, const float* __restrict__ Bm,
    const float* __restrict__ bias, void* __restrict__ Cptr,
    int Mdim, int Ndim, int Kdim)
{
  __shared__ float As[16][132];
  __shared__ float Bs[16][132];
  const int tid = threadIdx.x;
  const int row0 = blockIdx.y * 128;
  const int col0 = blockIdx.x * 128;
  const int tx = tid & 15, ty = tid >> 4;
  const int ar = tid >> 2, ac = (tid & 3) << 2;
  const int br = tid >> 5, bc = (tid & 31) << 2;
  float acc[8][8];
#pragma unroll
  for (int i = 0; i < 8; ++i)
#pragma unroll
    for (int j = 0; j < 8; ++j) acc[i][j] = 0.f;

  for (int k0 = 0; k0 < Kdim; k0 += 16) {
    float4 a0, a1;
    if constexpr (A_BF16) {
      const unsigned short* A = (const unsigned short*)Aptr;
      ushort4 u0 = *(const ushort4*)&A[(size_t)(row0 + ar) * Kdim + k0 + ac];
      ushort4 u1 = *(const ushort4*)&A[(size_t)(row0 + ar + 64) * Kdim + k0 + ac];
      a0 = make_float4(bf2f(u0.x), bf2f(u0.y), bf2f(u0.z), bf2f(u0.w));
      a1 = make_float4(bf2f(u1.x), bf2f(u1.y), bf2f(u1.z), bf2f(u1.w));
    } else {
      const float* A = (const float*)Aptr;
      a0 = *(const float4*)&A[(size_t)(row0 + ar) * Kdim + k0 + ac];
      a1 = *(const float4*)&A[(size_t)(row0 + ar + 64) * Kdim + k0 + ac];
    }
    float4 b0 = *(const float4*)&Bm[(size_t)(k0 + br) * Ndim + col0 + bc];
    float4 b1 = *(const float4*)&Bm[(size_t)(k0 + br + 8) * Ndim + col0 + bc];
    __syncthreads();
    As[ac + 0][ar] = a0.x; As[ac + 1][ar] = a0.y; As[ac + 2][ar] = a0.z; As[ac + 3][ar] = a0.w;
    As[ac + 0][ar + 64] = a1.x; As[ac + 1][ar + 64] = a1.y; As[ac + 2][ar + 64] = a1.z; As[ac + 3][ar + 64] = a1.w;
    *(float4*)&Bs[br][bc] = b0;
    *(float4*)&Bs[br + 8][bc] = b1;
    __syncthreads();
#pragma unroll
    for (int kk = 0; kk < 16; ++kk) {
      float af[8], bf[8];
      *(float4*)&af[0] = *(const float4*)&As[kk][ty * 4];
      *(float4*)&af[4] = *(const float4*)&As[kk][64 + ty * 4];
      *(float4*)&bf[0] = *(const float4*)&Bs[kk][tx * 4];
      *(float4*)&bf[4] = *(const float4*)&Bs[kk][64 + tx * 4];
#pragma unroll
      for (int i = 0; i < 8; ++i)
#pragma unroll
        for (int j = 0; j < 8; ++j)
          acc[i][j] = fmaf(af[i], bf[j], acc[i][j]);
    }
  }
#pragma unroll
  for (int i = 0; i < 8; ++i) {
    int r = row0 + ((i < 4) ? (ty * 4 + i) : (64 + ty * 4 + i - 4));
#pragma unroll
    for (int jh = 0; jh < 2; ++jh) {
      int c = col0 + jh * 64 + tx * 4;
      float v[4];
#pragma unroll
      for (int j = 0; j < 4; ++j) {
        v[j] = acc[i][jh * 4 + j];
        if (bias) v[j] += bias[c + j];
      }
      if constexpr (C_BF16) {
        unsigned short t[4];
#pragma unroll
        for (int j = 0; j < 4; ++j) t[j] = f2bf(v[j]);
        *(ushort4*)&((unsigned short*)Cptr)[(size_t)r * Ndim + c] = *(ushort4*)t;
      } else {
        *(float4*)&((float*)Cptr)[(size_t)r * Ndim + c] = *(float4*)v;
      }
    }
  }
}

// ---------------- K2: per-block max of key data_dash (raw dot) ----------------
__global__ __launch_bounds__(320) void kmax_partial(
    const unsigned short* __restrict__ qkv, const float* __restrict__ P,
    float* __restrict__ bmax)
{
  __shared__ float k_lds[128 * 64];
  __shared__ float red[5];
  const int tid = threadIdx.x;
  const int blk = blockIdx.x;
  const int bh = blk >> 5;
  const int tile = blk & 31;
  const int b = bh / H_, h = bh % H_;
  const int n0 = tile * 128;
  for (int idx = tid; idx < 128 * 64; idx += 320) {
    int r = idx >> 6, d = idx & 63;
    k_lds[idx] = bf2f(qkv[(size_t)(b * N_TOK + n0 + r) * TC_ + C_ + h * HD_ + d]);
  }
  __syncthreads();
  float vmax = NEG_INF;
  if (tid < M_) {
    float preg[64];
#pragma unroll
    for (int d = 0; d < 64; ++d) preg[d] = P[tid * 64 + d];
    for (int r = 0; r < 128; ++r) {
      float a0 = 0, a1 = 0, a2 = 0, a3 = 0;
#pragma unroll
      for (int d = 0; d < 64; d += 4) {
        a0 = fmaf(k_lds[r * 64 + d + 0], preg[d + 0], a0);
        a1 = fmaf(k_lds[r * 64 + d + 1], preg[d + 1], a1);
        a2 = fmaf(k_lds[r * 64 + d + 2], preg[d + 2], a2);
        a3 = fmaf(k_lds[r * 64 + d + 3], preg[d + 3], a3);
      }
      vmax = fmaxf(vmax, (a0 + a1) + (a2 + a3));
    }
  }
#pragma unroll
  for (int off = 32; off >= 1; off >>= 1) vmax = fmaxf(vmax, __shfl_xor(vmax, off));
  if ((tid & 63) == 0) red[tid >> 6] = vmax;
  __syncthreads();
  if (tid == 0) {
    float m = red[0];
    for (int w = 1; w < 5; ++w) m = fmaxf(m, red[w]);
    bmax[blk] = m;
  }
}

__global__ __launch_bounds__(256) void kmax_reduce(
    const float* __restrict__ bmax, float* __restrict__ kmaxp, int n)
{
  __shared__ float red[4];
  float v = NEG_INF;
  for (int i = threadIdx.x; i < n; i += 256) v = fmaxf(v, bmax[i]);
#pragma unroll
  for (int off = 32; off >= 1; off >>= 1) v = fmaxf(v, __shfl_xor(v, off));
  if ((threadIdx.x & 63) == 0) red[threadIdx.x >> 6] = v;
  __syncthreads();
  if (threadIdx.x == 0)
    kmaxp[0] = DN * fmaxf(fmaxf(red[0], red[1]), fmaxf(red[2], red[3]));
}

// ---------------- K3: k-features -> partial kv [266x64] and ksum [266] ----------------
__global__ __launch_bounds__(512) void kv_partial(
    const unsigned short* __restrict__ qkv, const float* __restrict__ P,
    const float* __restrict__ kmaxp,
    float* __restrict__ kvpart, float* __restrict__ ksumpart)
{
  __shared__ float P_lds[M_ * 68];
  __shared__ float k_lds[8 * 68];
  __shared__ float v_lds[8 * 68];
  __shared__ float k1_lds[8 * 272];
  __shared__ float diag_lds[8];
  const int tid = threadIdx.x;
  const int bh = blockIdx.x;
  const int chunk = blockIdx.y;
  const int b = bh / H_, h = bh % H_;
  const float stab = kmaxp[0];
  for (int idx = tid; idx < M_ * 64; idx += 512) {
    int r = idx >> 6, d = idx & 63;
    P_lds[r * 68 + d] = P[idx];
  }
  const int i_ = tid >> 4;   // 0..31  owns mm = i_ + 32t
  const int j_ = tid & 15;   // owns d = 4j_..4j_+3
  float kvacc[9][4];
  float ksacc[9];
#pragma unroll
  for (int t = 0; t < 9; ++t) {
    ksacc[t] = 0;
    kvacc[t][0] = 0; kvacc[t][1] = 0; kvacc[t][2] = 0; kvacc[t][3] = 0;
  }
  __syncthreads();
  for (int g = 0; g < 64; ++g) {
    const int n0 = chunk * 512 + g * 8;
    __syncthreads();   // previous group's k1/v reads done before restage
    {
      int r = tid >> 6, d = tid & 63;
      size_t base = (size_t)(b * N_TOK + n0 + r) * TC_ + h * HD_ + d;
      k_lds[r * 68 + d] = bf2f(qkv[base + C_]);
      v_lds[r * 68 + d] = bf2f(qkv[base + 2 * C_]);
    }
    __syncthreads();
    // raw dots: mm<266 -> dash dot; mm==266 -> self dot (diag)
    for (int idx = tid; idx < 8 * 267; idx += 512) {
      int mm = idx >> 3, r = idx & 7;
      const float* vec = (mm < M_) ? &P_lds[mm * 68] : &k_lds[r * 68];
      float a0 = 0, a1 = 0, a2 = 0, a3 = 0;
#pragma unroll
      for (int d = 0; d < 64; d += 4) {
        a0 = fmaf(k_lds[r * 68 + d + 0], vec[d + 0], a0);
        a1 = fmaf(k_lds[r * 68 + d + 1], vec[d + 1], a1);
        a2 = fmaf(k_lds[r * 68 + d + 2], vec[d + 2], a2);
        a3 = fmaf(k_lds[r * 68 + d + 3], vec[d + 3], a3);
      }
      float dot = (a0 + a1) + (a2 + a3);
      if (mm < M_) k1_lds[r * 272 + mm] = dot;
      else diag_lds[r] = dot * 0.0625f;
    }
    __syncthreads();
    for (int idx = tid; idx < 8 * M_; idx += 512) {
      int mm = idx >> 3, r = idx & 7;
      float dash = DN * k1_lds[r * 272 + mm];
      k1_lds[r * 272 + mm] = RATIO * (__expf(dash - diag_lds[r] - stab) + FEPS);
    }
    __syncthreads();
#pragma unroll
    for (int r = 0; r < 8; ++r) {
      float4 v4 = *(const float4*)&v_lds[r * 68 + j_ * 4];
#pragma unroll
      for (int t = 0; t < 9; ++t) {
        int mm = i_ + (t << 5);
        if (mm < M_) {
          float kk = k1_lds[r * 272 + mm];
          kvacc[t][0] = fmaf(kk, v4.x, kvacc[t][0]);
          kvacc[t][1] = fmaf(kk, v4.y, kvacc[t][1]);
          kvacc[t][2] = fmaf(kk, v4.z, kvacc[t][2]);
          kvacc[t][3] = fmaf(kk, v4.w, kvacc[t][3]);
          if (j_ == 0) ksacc[t] += kk;
        }
      }
    }
  }
  const size_t pbase = (size_t)(chunk * BH_ + bh) * M_;
#pragma unroll
  for (int t = 0; t < 9; ++t) {
    int mm = i_ + (t << 5);
    if (mm < M_) {
      float4 v4;
      v4.x = kvacc[t][0]; v4.y = kvacc[t][1]; v4.z = kvacc[t][2]; v4.w = kvacc[t][3];
      *(float4*)&kvpart[(pbase + mm) * 64 + j_ * 4] = v4;
      if (j_ == 0) ksumpart[pbase + mm] = ksacc[t];
    }
  }
}

// ---------------- K4: reduce partials ----------------
__global__ __launch_bounds__(256) void kv_reduce(
    const float* __restrict__ kvpart, const float* __restrict__ ksumpart,
    float* __restrict__ kv, float* __restrict__ ksum)
{
  const int KVN = BH_ * M_ * 64;
  const int KSN = BH_ * M_;
  int idx = blockIdx.x * 256 + threadIdx.x;
  if (idx < KVN) {
    float s = 0;
#pragma unroll
    for (int c = 0; c < 8; ++c) s += kvpart[(size_t)c * KVN + idx];
    kv[idx] = s;
  } else if (idx < KVN + KSN) {
    int j = idx - KVN;
    float s = 0;
#pragma unroll
    for (int c = 0; c < 8; ++c) s += ksumpart[(size_t)c * KSN + j];
    ksum[j] = s;
  }
}

// ---------------- K5: q-features + PV + normalize ----------------
__global__ __launch_bounds__(512) void attn_kernel(
    const unsigned short* __restrict__ qkv, const float* __restrict__ P,
    const float* __restrict__ kv, const float* __restrict__ ksum,
    unsigned short* __restrict__ attn)
{
  __shared__ float P_lds[M_ * 65];
  __shared__ float kv_lds[M_ * 64];
  __shared__ float ksum_lds[M_];
  __shared__ float q_lds[8 * 64];
  __shared__ float q1_lds[8 * 272];
  const int tid = threadIdx.x;
  const int bh = blockIdx.x;
  const int tile = blockIdx.y;
  const int b = bh / H_, h = bh % H_;
  for (int idx = tid; idx < M_ * 64; idx += 512) {
    int r = idx >> 6, d = idx & 63;
    P_lds[r * 65 + d] = P[idx];
    kv_lds[idx] = kv[(size_t)bh * M_ * 64 + idx];
  }
  for (int idx = tid; idx < M_; idx += 512) ksum_lds[idx] = ksum[bh * M_ + idx];
  __syncthreads();
  const int wid = tid >> 6, lane = tid & 63;
  for (int g = 0; g < 64; ++g) {
    const int n0 = tile * 512 + g * 8;
    __syncthreads();
    q_lds[tid] = bf2f(qkv[(size_t)(b * N_TOK + n0 + (tid >> 6)) * TC_ + h * HD_ + (tid & 63)]);
    __syncthreads();
    const int r = wid;
    float qreg[64];
#pragma unroll
    for (int d = 0; d < 64; ++d) qreg[d] = q_lds[r * 64 + d];
    float qv = q_lds[r * 64 + lane];
    float dq = qv * qv;
#pragma unroll
    for (int off = 32; off >= 1; off >>= 1) dq += __shfl_xor(dq, off);
    const float diag = dq * 0.0625f;
    float dash[5];
    float mx = NEG_INF;
#pragma unroll
    for (int t = 0; t < 5; ++t) {
      int mm = lane + (t << 6);
      if (mm < M_) {
        const float* pr = &P_lds[mm * 65];
        float a0 = 0, a1 = 0, a2 = 0, a3 = 0;
#pragma unroll
        for (int d = 0; d < 64; d += 4) {
          a0 = fmaf(qreg[d + 0], pr[d + 0], a0);
          a1 = fmaf(qreg[d + 1], pr[d + 1], a1);
          a2 = fmaf(qreg[d + 2], pr[d + 2], a2);
          a3 = fmaf(qreg[d + 3], pr[d + 3], a3);
        }
        dash[t] = DN * ((a0 + a1) + (a2 + a3));
        mx = fmaxf(mx, dash[t]);
      } else dash[t] = NEG_INF;
    }
#pragma unroll
    for (int off = 32; off >= 1; off >>= 1) mx = fmaxf(mx, __shfl_xor(mx, off));
    float zp = 0.f;
#pragma unroll
    for (int t = 0; t < 5; ++t) {
      int mm = lane + (t << 6);
      if (mm < M_) {
        float q1 = RATIO * (__expf(dash[t] - diag - mx) + FEPS);
        q1_lds[r * 272 + mm] = q1;
        zp = fmaf(q1, ksum_lds[mm], zp);
      }
    }
#pragma unroll
    for (int off = 32; off >= 1; off >>= 1) zp += __shfl_xor(zp, off);
    const float z = 1.0f / zp;
    float ac0 = 0, ac1 = 0, ac2 = 0, ac3 = 0;
    for (int mm = 0; mm < 264; mm += 4) {
      ac0 = fmaf(q1_lds[r * 272 + mm + 0], kv_lds[(mm + 0) * 64 + lane], ac0);
      ac1 = fmaf(q1_lds[r * 272 + mm + 1], kv_lds[(mm + 1) * 64 + lane], ac1);
      ac2 = fmaf(q1_lds[r * 272 + mm + 2], kv_lds[(mm + 2) * 64 + lane], ac2);
      ac3 = fmaf(q1_lds[r * 272 + mm + 3], kv_lds[(mm + 3) * 64 + lane], ac3);
    }
    ac0 = fmaf(q1_lds[r * 272 + 264], kv_lds[264 * 64 + lane], ac0);
    ac1 = fmaf(q1_lds[r * 272 + 265], kv_lds[265 * 64 + lane], ac1);
    float o = ((ac0 + ac1) + (ac2 + ac3)) * z;
    attn[(size_t)(b * N_TOK + n0 + r) * C_ + h * HD_ + lane] = f2bf(o);
  }
}

extern "C" void kernel_launch(void* const* d_in, const int* in_sizes, int n_in,
                              void* d_out, int out_size, void* d_ws, size_t ws_size,
                              hipStream_t stream) {
  const float* x     = (const float*)d_in[0];
  const float* Wqkv  = (const float*)d_in[1];
  const float* Wproj = (const float*)d_in[2];
  const float* bproj = (const float*)d_in[3];
  const float* P     = (const float*)d_in[4];
  float* out = (float*)d_out;
  float* ws = (float*)d_ws;

  // ws layout (f32 words), total ~52.7M words = 201 MiB
  unsigned short* qkv = (unsigned short*)ws;            // 75,497,472 bf16 = 37,748,736 words
  float* kvpart   = ws + 37748736;                      // 13,074,432 words
  float* ksumpart = ws + 50823168;                      // 204,288 words
  unsigned short* attn = (unsigned short*)(ws + 37748736); // 25,165,824 bf16 (overlaps dead kvpart)
  float* kvb      = ws + 51027456;                      // 1,634,304 words
  float* ksumb    = ws + 52661760;                      // 25,536 words
  float* bmax     = ws + 52687296;                      // 3,072 words
  float* kmaxp    = ws + 52690368;                      // 1 word

  sgemm128<0, 1><<<dim3(18, 256), 256, 0, stream>>>(x, Wqkv, nullptr, qkv, ROWS_, TC_, C_);
  kmax_partial<<<dim3(3072), 320, 0, stream>>>(qkv, P, bmax);
  kmax_reduce<<<dim3(1), 256, 0, stream>>>(bmax, kmaxp, 3072);
  kv_partial<<<dim3(96, 8), 512, 0, stream>>>(qkv, P, kmaxp, kvpart, ksumpart);
  kv_reduce<<<dim3(6484), 256, 0, stream>>>(kvpart, ksumpart, kvb, ksumb);
  attn_kernel<<<dim3(96, 8), 512, 0, stream>>>(qkv, P, kvb, ksumb, attn);
  sgemm128<1, 0><<<dim3(6, 256), 256, 0, stream>>>(attn, Wproj, bproj, out, ROWS_, C_, C_);
}

// Round 4
// 3212.386 us; speedup vs baseline: 1.5569x; 1.5569x over previous
//
#include <hip/hip_runtime.h>
#include <hip/hip_bf16.h>
#include <math.h>

#define B_ 8
#define N_TOK 4096
#define C_ 768
#define H_ 12
#define HD_ 64
#define M_ 266
#define TC_ 2304
#define BH_ 96
#define ROWS_ 32768

#define DN 0.35355339059327373f      // 1/sqrt(sqrt(64))
#define RATIO 0.06131393394849658f   // 1/sqrt(266)
#define FEPS 1e-4f
#define NEG_INF -3.0e38f

typedef __attribute__((ext_vector_type(4))) float f32x4;
typedef __attribute__((ext_vector_type(8))) short bf16x8;

__device__ __forceinline__ float bf2f(unsigned short u) {
  return __uint_as_float(((unsigned int)u) << 16);
}
__device__ __forceinline__ unsigned short f2bf(float f) {
  unsigned int x = __float_as_uint(f);
  unsigned int r = (x + 0x7fffu + ((x >> 16) & 1u)) >> 16;
  return (unsigned short)r;
}

#define GLOAD_LDS16(g, l) \
  __builtin_amdgcn_global_load_lds( \
      (const __attribute__((address_space(1))) void*)(g), \
      (__attribute__((address_space(3))) void*)(l), 16, 0, 0)

// ---------------- prep: cast f32 -> bf16 elementwise ----------------
__global__ __launch_bounds__(256) void cast_bf16(
    const float* __restrict__ src, unsigned short* __restrict__ dst, int n)
{
  int i = (blockIdx.x * 256 + threadIdx.x) * 4;
  if (i < n) {
    float4 v = *(const float4*)&src[i];
    ushort4 u;
    u.x = f2bf(v.x); u.y = f2bf(v.y); u.z = f2bf(v.z); u.w = f2bf(v.w);
    *(ushort4*)&dst[i] = u;
  }
}

// ---------------- prep: transpose + cast: src[R][Ccols] f32 -> dst[Ccols][R] bf16 ----------------
__global__ __launch_bounds__(256) void transpose_cast(
    const float* __restrict__ src, unsigned short* __restrict__ dst,
    int R, int Ccols)
{
  __shared__ float t[32][33];
  const int c0 = blockIdx.x * 32, r0 = blockIdx.y * 32;
  const int tx = threadIdx.x & 31, ty = threadIdx.x >> 5;  // ty 0..7
#pragma unroll
  for (int i = 0; i < 32; i += 8)
    t[ty + i][tx] = src[(size_t)(r0 + ty + i) * Ccols + c0 + tx];
  __syncthreads();
#pragma unroll
  for (int i = 0; i < 32; i += 8)
    dst[(size_t)(c0 + ty + i) * R + r0 + tx] = f2bf(t[tx][ty + i]);
}

// ---------------- MFMA GEMM: C[M,N] = A[M,K]bf16 x Bt[N,K]bf16 ----------------
// m97 structure: 128x128 tile, BK=32, 4 waves (each 64x64), global_load_lds width=16.
template <int C_BF16, int HAS_BIAS>
__global__ __launch_bounds__(256) void gemm_bf16(
    const unsigned short* __restrict__ A, const unsigned short* __restrict__ Bt,
    const float* __restrict__ bias, void* __restrict__ Cptr,
    int Mdim, int Ndim, int Kdim)
{
  __shared__ unsigned short Asm[128 * 32];
  __shared__ unsigned short Bsm[128 * 32];
  const int tid = threadIdx.x;
  const int wid = tid >> 6, lane = tid & 63;
  const int row0 = blockIdx.y * 128, col0 = blockIdx.x * 128;
  const int wr = (wid >> 1) * 64, wc = (wid & 1) * 64;

  f32x4 acc[4][4];
  const f32x4 fz = {0.f, 0.f, 0.f, 0.f};
#pragma unroll
  for (int m = 0; m < 4; ++m)
#pragma unroll
    for (int n = 0; n < 4; ++n) acc[m][n] = fz;

  // staging: wave wid covers LDS bytes [wid*2048, wid*2048+2048) in two 1KB calls
  // byte = wid*2048 + c*1024 + lane*16 -> row = wid*32 + c*16 + (lane>>2), k8 = (lane&3)*8
  const unsigned short* agp = A + (size_t)(row0 + (wid << 5) + (lane >> 2)) * Kdim + ((lane & 3) << 3);
  const unsigned short* bgp = Bt + (size_t)(col0 + (wid << 5) + (lane >> 2)) * Kdim + ((lane & 3) << 3);
  unsigned short* alp = Asm + (wid << 10) + (lane << 3);
  unsigned short* blp = Bsm + (wid << 10) + (lane << 3);
  const size_t rstep = (size_t)16 * Kdim;

  const int fr = lane & 15;          // fragment row (A) / col (B)
  const int fk = (lane >> 4) << 3;   // k offset within BK

  for (int k0 = 0; k0 < Kdim; k0 += 32) {
    __syncthreads();
    GLOAD_LDS16(agp, alp);
    GLOAD_LDS16(agp + rstep, alp + 512);
    GLOAD_LDS16(bgp, blp);
    GLOAD_LDS16(bgp + rstep, blp + 512);
    agp += 32; bgp += 32;
    __syncthreads();
    bf16x8 av[4], bv[4];
#pragma unroll
    for (int m = 0; m < 4; ++m)
      av[m] = *(const bf16x8*)&Asm[(wr + m * 16 + fr) * 32 + fk];
#pragma unroll
    for (int n = 0; n < 4; ++n)
      bv[n] = *(const bf16x8*)&Bsm[(wc + n * 16 + fr) * 32 + fk];
#pragma unroll
    for (int m = 0; m < 4; ++m)
#pragma unroll
      for (int n = 0; n < 4; ++n)
        acc[m][n] = __builtin_amdgcn_mfma_f32_16x16x32_bf16(av[m], bv[n], acc[m][n], 0, 0, 0);
  }

  const int orow = (lane >> 4) << 2;
#pragma unroll
  for (int m = 0; m < 4; ++m) {
#pragma unroll
    for (int n = 0; n < 4; ++n) {
      const int c = col0 + wc + n * 16 + fr;
      float badd = 0.f;
      if constexpr (HAS_BIAS) badd = bias[c];
#pragma unroll
      for (int j = 0; j < 4; ++j) {
        const int r = row0 + wr + m * 16 + orow + j;
        float v = acc[m][n][j] + badd;
        if constexpr (C_BF16)
          ((unsigned short*)Cptr)[(size_t)r * Ndim + c] = f2bf(v);
        else
          ((float*)Cptr)[(size_t)r * Ndim + c] = v;
      }
    }
  }
}

// ---------------- K2: per-block max of key data_dash (raw dot) ----------------
__global__ __launch_bounds__(320) void kmax_partial(
    const unsigned short* __restrict__ qkv, const float* __restrict__ P,
    float* __restrict__ bmax)
{
  __shared__ float k_lds[128 * 64];
  __shared__ float red[5];
  const int tid = threadIdx.x;
  const int blk = blockIdx.x;
  const int bh = blk >> 5;
  const int tile = blk & 31;
  const int b = bh / H_, h = bh % H_;
  const int n0 = tile * 128;
  for (int idx = tid; idx < 128 * 64; idx += 320) {
    int r = idx >> 6, d = idx & 63;
    k_lds[idx] = bf2f(qkv[(size_t)(b * N_TOK + n0 + r) * TC_ + C_ + h * HD_ + d]);
  }
  __syncthreads();
  float vmax = NEG_INF;
  if (tid < M_) {
    float preg[64];
#pragma unroll
    for (int d = 0; d < 64; ++d) preg[d] = P[tid * 64 + d];
    for (int r = 0; r < 128; ++r) {
      float a0 = 0, a1 = 0, a2 = 0, a3 = 0;
#pragma unroll
      for (int d = 0; d < 64; d += 4) {
        a0 = fmaf(k_lds[r * 64 + d + 0], preg[d + 0], a0);
        a1 = fmaf(k_lds[r * 64 + d + 1], preg[d + 1], a1);
        a2 = fmaf(k_lds[r * 64 + d + 2], preg[d + 2], a2);
        a3 = fmaf(k_lds[r * 64 + d + 3], preg[d + 3], a3);
      }
      vmax = fmaxf(vmax, (a0 + a1) + (a2 + a3));
    }
  }
#pragma unroll
  for (int off = 32; off >= 1; off >>= 1) vmax = fmaxf(vmax, __shfl_xor(vmax, off));
  if ((tid & 63) == 0) red[tid >> 6] = vmax;
  __syncthreads();
  if (tid == 0) {
    float m = red[0];
    for (int w = 1; w < 5; ++w) m = fmaxf(m, red[w]);
    bmax[blk] = m;
  }
}

__global__ __launch_bounds__(256) void kmax_reduce(
    const float* __restrict__ bmax, float* __restrict__ kmaxp, int n)
{
  __shared__ float red[4];
  float v = NEG_INF;
  for (int i = threadIdx.x; i < n; i += 256) v = fmaxf(v, bmax[i]);
#pragma unroll
  for (int off = 32; off >= 1; off >>= 1) v = fmaxf(v, __shfl_xor(v, off));
  if ((threadIdx.x & 63) == 0) red[threadIdx.x >> 6] = v;
  __syncthreads();
  if (threadIdx.x == 0)
    kmaxp[0] = DN * fmaxf(fmaxf(red[0], red[1]), fmaxf(red[2], red[3]));
}

// ---------------- K3: k-features -> partial kv [266x64] and ksum [266] ----------------
__global__ __launch_bounds__(512) void kv_partial(
    const unsigned short* __restrict__ qkv, const float* __restrict__ P,
    const float* __restrict__ kmaxp,
    float* __restrict__ kvpart, float* __restrict__ ksumpart)
{
  __shared__ float P_lds[M_ * 68];
  __shared__ float k_lds[8 * 68];
  __shared__ float v_lds[8 * 68];
  __shared__ float k1_lds[8 * 272];
  __shared__ float diag_lds[8];
  const int tid = threadIdx.x;
  const int bh = blockIdx.x;
  const int chunk = blockIdx.y;
  const int b = bh / H_, h = bh % H_;
  const float stab = kmaxp[0];
  for (int idx = tid; idx < M_ * 64; idx += 512) {
    int r = idx >> 6, d = idx & 63;
    P_lds[r * 68 + d] = P[idx];
  }
  const int i_ = tid >> 4;
  const int j_ = tid & 15;
  float kvacc[9][4];
  float ksacc[9];
#pragma unroll
  for (int t = 0; t < 9; ++t) {
    ksacc[t] = 0;
    kvacc[t][0] = 0; kvacc[t][1] = 0; kvacc[t][2] = 0; kvacc[t][3] = 0;
  }
  __syncthreads();
  for (int g = 0; g < 64; ++g) {
    const int n0 = chunk * 512 + g * 8;
    __syncthreads();
    {
      int r = tid >> 6, d = tid & 63;
      size_t base = (size_t)(b * N_TOK + n0 + r) * TC_ + h * HD_ + d;
      k_lds[r * 68 + d] = bf2f(qkv[base + C_]);
      v_lds[r * 68 + d] = bf2f(qkv[base + 2 * C_]);
    }
    __syncthreads();
    for (int idx = tid; idx < 8 * 267; idx += 512) {
      int mm = idx >> 3, r = idx & 7;
      const float* vec = (mm < M_) ? &P_lds[mm * 68] : &k_lds[r * 68];
      float a0 = 0, a1 = 0, a2 = 0, a3 = 0;
#pragma unroll
      for (int d = 0; d < 64; d += 4) {
        a0 = fmaf(k_lds[r * 68 + d + 0], vec[d + 0], a0);
        a1 = fmaf(k_lds[r * 68 + d + 1], vec[d + 1], a1);
        a2 = fmaf(k_lds[r * 68 + d + 2], vec[d + 2], a2);
        a3 = fmaf(k_lds[r * 68 + d + 3], vec[d + 3], a3);
      }
      float dot = (a0 + a1) + (a2 + a3);
      if (mm < M_) k1_lds[r * 272 + mm] = dot;
      else diag_lds[r] = dot * 0.0625f;
    }
    __syncthreads();
    for (int idx = tid; idx < 8 * M_; idx += 512) {
      int mm = idx >> 3, r = idx & 7;
      float dash = DN * k1_lds[r * 272 + mm];
      k1_lds[r * 272 + mm] = RATIO * (__expf(dash - diag_lds[r] - stab) + FEPS);
    }
    __syncthreads();
#pragma unroll
    for (int r = 0; r < 8; ++r) {
      float4 v4 = *(const float4*)&v_lds[r * 68 + j_ * 4];
#pragma unroll
      for (int t = 0; t < 9; ++t) {
        int mm = i_ + (t << 5);
        if (mm < M_) {
          float kk = k1_lds[r * 272 + mm];
          kvacc[t][0] = fmaf(kk, v4.x, kvacc[t][0]);
          kvacc[t][1] = fmaf(kk, v4.y, kvacc[t][1]);
          kvacc[t][2] = fmaf(kk, v4.z, kvacc[t][2]);
          kvacc[t][3] = fmaf(kk, v4.w, kvacc[t][3]);
          if (j_ == 0) ksacc[t] += kk;
        }
      }
    }
  }
  const size_t pbase = (size_t)(chunk * BH_ + bh) * M_;
#pragma unroll
  for (int t = 0; t < 9; ++t) {
    int mm = i_ + (t << 5);
    if (mm < M_) {
      float4 v4;
      v4.x = kvacc[t][0]; v4.y = kvacc[t][1]; v4.z = kvacc[t][2]; v4.w = kvacc[t][3];
      *(float4*)&kvpart[(pbase + mm) * 64 + j_ * 4] = v4;
      if (j_ == 0) ksumpart[pbase + mm] = ksacc[t];
    }
  }
}

// ---------------- K4: reduce partials ----------------
__global__ __launch_bounds__(256) void kv_reduce(
    const float* __restrict__ kvpart, const float* __restrict__ ksumpart,
    float* __restrict__ kv, float* __restrict__ ksum)
{
  const int KVN = BH_ * M_ * 64;
  const int KSN = BH_ * M_;
  int idx = blockIdx.x * 256 + threadIdx.x;
  if (idx < KVN) {
    float s = 0;
#pragma unroll
    for (int c = 0; c < 8; ++c) s += kvpart[(size_t)c * KVN + idx];
    kv[idx] = s;
  } else if (idx < KVN + KSN) {
    int j = idx - KVN;
    float s = 0;
#pragma unroll
    for (int c = 0; c < 8; ++c) s += ksumpart[(size_t)c * KSN + j];
    ksum[j] = s;
  }
}

// ---------------- K5: q-features + PV + normalize ----------------
__global__ __launch_bounds__(512) void attn_kernel(
    const unsigned short* __restrict__ qkv, const float* __restrict__ P,
    const float* __restrict__ kv, const float* __restrict__ ksum,
    unsigned short* __restrict__ attn)
{
  __shared__ float P_lds[M_ * 65];
  __shared__ float kv_lds[M_ * 64];
  __shared__ float ksum_lds[M_];
  __shared__ float q_lds[8 * 64];
  __shared__ float q1_lds[8 * 272];
  const int tid = threadIdx.x;
  const int bh = blockIdx.x;
  const int tile = blockIdx.y;
  const int b = bh / H_, h = bh % H_;
  for (int idx = tid; idx < M_ * 64; idx += 512) {
    int r = idx >> 6, d = idx & 63;
    P_lds[r * 65 + d] = P[idx];
    kv_lds[idx] = kv[(size_t)bh * M_ * 64 + idx];
  }
  for (int idx = tid; idx < M_; idx += 512) ksum_lds[idx] = ksum[bh * M_ + idx];
  __syncthreads();
  const int wid = tid >> 6, lane = tid & 63;
  for (int g = 0; g < 64; ++g) {
    const int n0 = tile * 512 + g * 8;
    __syncthreads();
    q_lds[tid] = bf2f(qkv[(size_t)(b * N_TOK + n0 + (tid >> 6)) * TC_ + h * HD_ + (tid & 63)]);
    __syncthreads();
    const int r = wid;
    float qreg[64];
#pragma unroll
    for (int d = 0; d < 64; ++d) qreg[d] = q_lds[r * 64 + d];
    float qv = q_lds[r * 64 + lane];
    float dq = qv * qv;
#pragma unroll
    for (int off = 32; off >= 1; off >>= 1) dq += __shfl_xor(dq, off);
    const float diag = dq * 0.0625f;
    float dash[5];
    float mx = NEG_INF;
#pragma unroll
    for (int t = 0; t < 5; ++t) {
      int mm = lane + (t << 6);
      if (mm < M_) {
        const float* pr = &P_lds[mm * 65];
        float a0 = 0, a1 = 0, a2 = 0, a3 = 0;
#pragma unroll
        for (int d = 0; d < 64; d += 4) {
          a0 = fmaf(qreg[d + 0], pr[d + 0], a0);
          a1 = fmaf(qreg[d + 1], pr[d + 1], a1);
          a2 = fmaf(qreg[d + 2], pr[d + 2], a2);
          a3 = fmaf(qreg[d + 3], pr[d + 3], a3);
        }
        dash[t] = DN * ((a0 + a1) + (a2 + a3));
        mx = fmaxf(mx, dash[t]);
      } else dash[t] = NEG_INF;
    }
#pragma unroll
    for (int off = 32; off >= 1; off >>= 1) mx = fmaxf(mx, __shfl_xor(mx, off));
    float zp = 0.f;
#pragma unroll
    for (int t = 0; t < 5; ++t) {
      int mm = lane + (t << 6);
      if (mm < M_) {
        float q1 = RATIO * (__expf(dash[t] - diag - mx) + FEPS);
        q1_lds[r * 272 + mm] = q1;
        zp = fmaf(q1, ksum_lds[mm], zp);
      }
    }
#pragma unroll
    for (int off = 32; off >= 1; off >>= 1) zp += __shfl_xor(zp, off);
    const float z = 1.0f / zp;
    float ac0 = 0, ac1 = 0, ac2 = 0, ac3 = 0;
    for (int mm = 0; mm < 264; mm += 4) {
      ac0 = fmaf(q1_lds[r * 272 + mm + 0], kv_lds[(mm + 0) * 64 + lane], ac0);
      ac1 = fmaf(q1_lds[r * 272 + mm + 1], kv_lds[(mm + 1) * 64 + lane], ac1);
      ac2 = fmaf(q1_lds[r * 272 + mm + 2], kv_lds[(mm + 2) * 64 + lane], ac2);
      ac3 = fmaf(q1_lds[r * 272 + mm + 3], kv_lds[(mm + 3) * 64 + lane], ac3);
    }
    ac0 = fmaf(q1_lds[r * 272 + 264], kv_lds[264 * 64 + lane], ac0);
    ac1 = fmaf(q1_lds[r * 272 + 265], kv_lds[265 * 64 + lane], ac1);
    float o = ((ac0 + ac1) + (ac2 + ac3)) * z;
    attn[(size_t)(b * N_TOK + n0 + r) * C_ + h * HD_ + lane] = f2bf(o);
  }
}

extern "C" void kernel_launch(void* const* d_in, const int* in_sizes, int n_in,
                              void* d_out, int out_size, void* d_ws, size_t ws_size,
                              hipStream_t stream) {
  const float* x     = (const float*)d_in[0];
  const float* Wqkv  = (const float*)d_in[1];
  const float* Wproj = (const float*)d_in[2];
  const float* bproj = (const float*)d_in[3];
  const float* P     = (const float*)d_in[4];
  float* out = (float*)d_out;
  float* ws = (float*)d_ws;

  // ws layout (f32 words), total 53,870,080 words = 215.5 MiB
  unsigned short* qkv = (unsigned short*)ws;               // 75,497,472 bf16
  // region Z (reused sequentially): xb -> kvpart -> attn
  unsigned short* xb   = (unsigned short*)(ws + 37748736); // 25,165,824 bf16
  float* kvpart   = ws + 37748736;                         // 13,074,432 words
  unsigned short* attn = (unsigned short*)(ws + 37748736); // 25,165,824 bf16
  float* ksumpart = ws + 50823168;                         // 204,288 words
  float* kvb      = ws + 51027456;                         // 1,634,304 words
  float* ksumb    = ws + 52661760;                         // 25,536 words
  float* bmax     = ws + 52687296;                         // 3,072 words
  float* kmaxp    = ws + 52690368;                         // 1 word
  unsigned short* Wqkvt  = (unsigned short*)(ws + 52690432); // 1,769,472 bf16
  unsigned short* Wprojt = (unsigned short*)(ws + 53575168); // 589,824 bf16

  cast_bf16<<<dim3(24576), 256, 0, stream>>>(x, xb, ROWS_ * C_);
  transpose_cast<<<dim3(72, 24), 256, 0, stream>>>(Wqkv, Wqkvt, C_, TC_);
  transpose_cast<<<dim3(24, 24), 256, 0, stream>>>(Wproj, Wprojt, C_, C_);

  gemm_bf16<1, 0><<<dim3(18, 256), 256, 0, stream>>>(xb, Wqkvt, nullptr, qkv, ROWS_, TC_, C_);
  kmax_partial<<<dim3(3072), 320, 0, stream>>>(qkv, P, bmax);
  kmax_reduce<<<dim3(1), 256, 0, stream>>>(bmax, kmaxp, 3072);
  kv_partial<<<dim3(96, 8), 512, 0, stream>>>(qkv, P, kmaxp, kvpart, ksumpart);
  kv_reduce<<<dim3(6484), 256, 0, stream>>>(kvpart, ksumpart, kvb, ksumb);
  attn_kernel<<<dim3(96, 8), 512, 0, stream>>>(qkv, P, kvb, ksumb, attn);
  gemm_bf16<0, 1><<<dim3(6, 256), 256, 0, stream>>>(attn, Wprojt, bproj, out, ROWS_, C_, C_);
}

// Round 5
// 1285.839 us; speedup vs baseline: 3.8895x; 2.4983x over previous
//
#include <hip/hip_runtime.h>
#include <hip/hip_bf16.h>
#include <math.h>

#define B_ 8
#define N_TOK 4096
#define C_ 768
#define H_ 12
#define HD_ 64
#define M_ 266
#define TC_ 2304
#define BH_ 96
#define ROWS_ 32768

#define M2 288          // padded m-dim (9 ksteps x 32)
#define MP 296          // LDS m-stride (u16), 2-way-free banks
#define KVS 72          // LDS stride for K/Vt/k1 (u16)

#define DN 0.35355339059327373f      // 1/sqrt(sqrt(64))
#define RATIO 0.06131393394849658f   // 1/sqrt(266)
#define FEPS 1e-4f
#define NEG_INF -3.0e38f

typedef __attribute__((ext_vector_type(4))) float f32x4;
typedef __attribute__((ext_vector_type(8))) short bf16x8;

__device__ __forceinline__ float bf2f(unsigned short u) {
  return __uint_as_float(((unsigned int)u) << 16);
}
__device__ __forceinline__ unsigned short f2bf(float f) {
  unsigned int x = __float_as_uint(f);
  unsigned int r = (x + 0x7fffu + ((x >> 16) & 1u)) >> 16;
  return (unsigned short)r;
}

#define GLOAD_LDS16(g, l) \
  __builtin_amdgcn_global_load_lds( \
      (const __attribute__((address_space(1))) void*)(g), \
      (__attribute__((address_space(3))) void*)(l), 16, 0, 0)

// ---------------- prep: cast f32 -> bf16 elementwise ----------------
__global__ __launch_bounds__(256) void cast_bf16(
    const float* __restrict__ src, unsigned short* __restrict__ dst, int n)
{
  int i = (blockIdx.x * 256 + threadIdx.x) * 4;
  if (i < n) {
    float4 v = *(const float4*)&src[i];
    ushort4 u;
    u.x = f2bf(v.x); u.y = f2bf(v.y); u.z = f2bf(v.z); u.w = f2bf(v.w);
    *(ushort4*)&dst[i] = u;
  }
}

// ---------------- prep: P [266][64] f32 -> Pbf [288][64] bf16 (zero-padded) ----
__global__ __launch_bounds__(256) void cast_pbf(
    const float* __restrict__ P, unsigned short* __restrict__ Pbf)
{
  int idx = blockIdx.x * 256 + threadIdx.x;
  if (idx < M2 * 64) {
    int m = idx >> 6;
    Pbf[idx] = (m < M_) ? f2bf(P[idx]) : (unsigned short)0;
  }
}

// ---------------- prep: transpose + cast: src[R][Ccols] f32 -> dst[Ccols][R] bf16 ----
__global__ __launch_bounds__(256) void transpose_cast(
    const float* __restrict__ src, unsigned short* __restrict__ dst,
    int R, int Ccols)
{
  __shared__ float t[32][33];
  const int c0 = blockIdx.x * 32, r0 = blockIdx.y * 32;
  const int tx = threadIdx.x & 31, ty = threadIdx.x >> 5;
#pragma unroll
  for (int i = 0; i < 32; i += 8)
    t[ty + i][tx] = src[(size_t)(r0 + ty + i) * Ccols + c0 + tx];
  __syncthreads();
#pragma unroll
  for (int i = 0; i < 32; i += 8)
    dst[(size_t)(c0 + ty + i) * R + r0 + tx] = f2bf(t[tx][ty + i]);
}

// ---------------- MFMA GEMM: C[M,N] = A[M,K]bf16 x Bt[N,K]bf16 ----------------
template <int C_BF16, int HAS_BIAS>
__global__ __launch_bounds__(256) void gemm_bf16(
    const unsigned short* __restrict__ A, const unsigned short* __restrict__ Bt,
    const float* __restrict__ bias, void* __restrict__ Cptr,
    int Mdim, int Ndim, int Kdim)
{
  __shared__ unsigned short Asm[128 * 32];
  __shared__ unsigned short Bsm[128 * 32];
  const int tid = threadIdx.x;
  const int wid = tid >> 6, lane = tid & 63;
  const int row0 = blockIdx.y * 128, col0 = blockIdx.x * 128;
  const int wr = (wid >> 1) * 64, wc = (wid & 1) * 64;

  f32x4 acc[4][4];
  const f32x4 fz = {0.f, 0.f, 0.f, 0.f};
#pragma unroll
  for (int m = 0; m < 4; ++m)
#pragma unroll
    for (int n = 0; n < 4; ++n) acc[m][n] = fz;

  const unsigned short* agp = A + (size_t)(row0 + (wid << 5) + (lane >> 2)) * Kdim + ((lane & 3) << 3);
  const unsigned short* bgp = Bt + (size_t)(col0 + (wid << 5) + (lane >> 2)) * Kdim + ((lane & 3) << 3);
  unsigned short* alp = Asm + (wid << 10) + (lane << 3);
  unsigned short* blp = Bsm + (wid << 10) + (lane << 3);
  const size_t rstep = (size_t)16 * Kdim;

  const int fr = lane & 15;
  const int fk = (lane >> 4) << 3;

  for (int k0 = 0; k0 < Kdim; k0 += 32) {
    __syncthreads();
    GLOAD_LDS16(agp, alp);
    GLOAD_LDS16(agp + rstep, alp + 512);
    GLOAD_LDS16(bgp, blp);
    GLOAD_LDS16(bgp + rstep, blp + 512);
    agp += 32; bgp += 32;
    __syncthreads();
    bf16x8 av[4], bv[4];
#pragma unroll
    for (int m = 0; m < 4; ++m)
      av[m] = *(const bf16x8*)&Asm[(wr + m * 16 + fr) * 32 + fk];
#pragma unroll
    for (int n = 0; n < 4; ++n)
      bv[n] = *(const bf16x8*)&Bsm[(wc + n * 16 + fr) * 32 + fk];
#pragma unroll
    for (int m = 0; m < 4; ++m)
#pragma unroll
      for (int n = 0; n < 4; ++n)
        acc[m][n] = __builtin_amdgcn_mfma_f32_16x16x32_bf16(av[m], bv[n], acc[m][n], 0, 0, 0);
  }

  const int orow = (lane >> 4) << 2;
#pragma unroll
  for (int m = 0; m < 4; ++m) {
#pragma unroll
    for (int n = 0; n < 4; ++n) {
      const int c = col0 + wc + n * 16 + fr;
      float badd = 0.f;
      if constexpr (HAS_BIAS) badd = bias[c];
#pragma unroll
      for (int j = 0; j < 4; ++j) {
        const int r = row0 + wr + m * 16 + orow + j;
        float v = acc[m][n][j] + badd;
        if constexpr (C_BF16)
          ((unsigned short*)Cptr)[(size_t)r * Ndim + c] = f2bf(v);
        else
          ((float*)Cptr)[(size_t)r * Ndim + c] = v;
      }
    }
  }
}

// ---------------- K2: per-block max of key data_dash (raw dot) ----------------
__global__ __launch_bounds__(320) void kmax_partial(
    const unsigned short* __restrict__ qkv, const float* __restrict__ P,
    float* __restrict__ bmax)
{
  __shared__ float k_lds[128 * 64];
  __shared__ float red[5];
  const int tid = threadIdx.x;
  const int blk = blockIdx.x;
  const int bh = blk >> 5;
  const int tile = blk & 31;
  const int b = bh / H_, h = bh % H_;
  const int n0 = tile * 128;
  for (int idx = tid; idx < 128 * 64; idx += 320) {
    int r = idx >> 6, d = idx & 63;
    k_lds[idx] = bf2f(qkv[(size_t)(b * N_TOK + n0 + r) * TC_ + C_ + h * HD_ + d]);
  }
  __syncthreads();
  float vmax = NEG_INF;
  if (tid < M_) {
    float preg[64];
#pragma unroll
    for (int d = 0; d < 64; ++d) preg[d] = P[tid * 64 + d];
    for (int r = 0; r < 128; ++r) {
      float a0 = 0, a1 = 0, a2 = 0, a3 = 0;
#pragma unroll
      for (int d = 0; d < 64; d += 4) {
        a0 = fmaf(k_lds[r * 64 + d + 0], preg[d + 0], a0);
        a1 = fmaf(k_lds[r * 64 + d + 1], preg[d + 1], a1);
        a2 = fmaf(k_lds[r * 64 + d + 2], preg[d + 2], a2);
        a3 = fmaf(k_lds[r * 64 + d + 3], preg[d + 3], a3);
      }
      vmax = fmaxf(vmax, (a0 + a1) + (a2 + a3));
    }
  }
#pragma unroll
  for (int off = 32; off >= 1; off >>= 1) vmax = fmaxf(vmax, __shfl_xor(vmax, off));
  if ((tid & 63) == 0) red[tid >> 6] = vmax;
  __syncthreads();
  if (tid == 0) {
    float m = red[0];
    for (int w = 1; w < 5; ++w) m = fmaxf(m, red[w]);
    bmax[blk] = m;
  }
}

__global__ __launch_bounds__(256) void kmax_reduce(
    const float* __restrict__ bmax, float* __restrict__ kmaxp, int n)
{
  __shared__ float red[4];
  float v = NEG_INF;
  for (int i = threadIdx.x; i < n; i += 256) v = fmaxf(v, bmax[i]);
#pragma unroll
  for (int off = 32; off >= 1; off >>= 1) v = fmaxf(v, __shfl_xor(v, off));
  if ((threadIdx.x & 63) == 0) red[threadIdx.x >> 6] = v;
  __syncthreads();
  if (threadIdx.x == 0)
    kmaxp[0] = DN * fmaxf(fmaxf(red[0], red[1]), fmaxf(red[2], red[3]));
}

// ---------------- K3: MFMA k-features -> partial kv^T [64 d][288 m] + ksum ----
__global__ __launch_bounds__(256) void kv_partial_mfma(
    const unsigned short* __restrict__ qkv, const unsigned short* __restrict__ Pbf,
    const float* __restrict__ kmaxp,
    float* __restrict__ kvpart, float* __restrict__ ksumpart)
{
  __shared__ unsigned short K_lds[64 * KVS];
  __shared__ unsigned short Vt_lds[64 * KVS];
  __shared__ unsigned short k1_lds[272 * KVS];
  __shared__ float diag_lds[64];
  const int tid = threadIdx.x;
  const int w = tid >> 6, lane = tid & 63;
  const int lr = lane & 15, q = lane >> 4;
  const int bh = blockIdx.x, chunk = blockIdx.y;
  const int b = bh / H_, h = bh % H_;
  const float stab = kmaxp[0];
  const int ms = w * 4;                  // first mtile of this wave
  const int mc = (w == 3) ? 5 : 4;       // mtile count (17 total)

  f32x4 kvacc[5][4];
  float ksacc[5];
  const f32x4 fz = {0.f, 0.f, 0.f, 0.f};
#pragma unroll
  for (int i = 0; i < 5; ++i) {
    ksacc[i] = 0.f;
#pragma unroll
    for (int dt = 0; dt < 4; ++dt) kvacc[i][dt] = fz;
  }

  // staging indices: wave w stages rows 16w..16w+15
  const int sn = 16 * w + (lane >> 2);
  const int sd0 = (lane & 3) * 16;

  for (int g = 0; g < 8; ++g) {
    const int nb = chunk * 512 + g * 64;
    __syncthreads();
    {
      const unsigned short* kr = qkv + (size_t)(b * N_TOK + nb + sn) * TC_ + C_ + h * HD_ + sd0;
      int4 k0 = *(const int4*)kr;
      int4 k1v = *(const int4*)(kr + 8);
      *(int4*)&K_lds[sn * KVS + sd0] = k0;
      *(int4*)&K_lds[sn * KVS + sd0 + 8] = k1v;
      // diag partial from the 16 staged values
      const unsigned short* pk = (const unsigned short*)&k0;
      float sq = 0.f;
#pragma unroll
      for (int j = 0; j < 8; ++j) { float f = bf2f(pk[j]); sq = fmaf(f, f, sq); }
      const unsigned short* pk1 = (const unsigned short*)&k1v;
#pragma unroll
      for (int j = 0; j < 8; ++j) { float f = bf2f(pk1[j]); sq = fmaf(f, f, sq); }
      sq += __shfl_xor(sq, 1);
      sq += __shfl_xor(sq, 2);
      if ((lane & 3) == 0) diag_lds[sn] = 0.0625f * sq;
      // V transposed
      const unsigned short* vr = kr + C_;
      int4 v0 = *(const int4*)vr;
      int4 v1 = *(const int4*)(vr + 8);
      const unsigned short* pv0 = (const unsigned short*)&v0;
      const unsigned short* pv1 = (const unsigned short*)&v1;
#pragma unroll
      for (int j = 0; j < 8; ++j) Vt_lds[(sd0 + j) * KVS + sn] = pv0[j];
#pragma unroll
      for (int j = 0; j < 8; ++j) Vt_lds[(sd0 + 8 + j) * KVS + sn] = pv1[j];
    }
    __syncthreads();

    // K B-frags (A-operand of S), hoisted
    bf16x8 bk[4][2];
#pragma unroll
    for (int nt = 0; nt < 4; ++nt)
#pragma unroll
      for (int ks = 0; ks < 2; ++ks)
        bk[nt][ks] = *(const bf16x8*)&K_lds[(nt * 16 + lr) * KVS + ks * 32 + q * 8];

    // S-step: this wave's mtiles; C[n][m] col=m=lane&15
#pragma unroll
    for (int i = 0; i < 5; ++i) {
      if (i >= mc) continue;
      const int mt = ms + i;
      const int m = mt * 16 + lr;
      const unsigned short* prow = Pbf + (size_t)m * 64;
      bf16x8 ap0 = *(const bf16x8*)(prow + q * 8);
      bf16x8 ap1 = *(const bf16x8*)(prow + q * 8 + 32);
      float loc = 0.f;
#pragma unroll
      for (int nt = 0; nt < 4; ++nt) {
        f32x4 s = fz;
        s = __builtin_amdgcn_mfma_f32_16x16x32_bf16(bk[nt][0], ap0, s, 0, 0, 0);
        s = __builtin_amdgcn_mfma_f32_16x16x32_bf16(bk[nt][1], ap1, s, 0, 0, 0);
        ushort4 uo;
        unsigned short* puo = (unsigned short*)&uo;
#pragma unroll
        for (int j = 0; j < 4; ++j) {
          const int nl = nt * 16 + q * 4 + j;
          float k1f = 0.f;
          if (m < M_) {
            float dash = DN * s[j];
            k1f = RATIO * (__expf(dash - diag_lds[nl] - stab) + FEPS);
          }
          loc += k1f;
          puo[j] = f2bf(k1f);
        }
        *(ushort4*)&k1_lds[(size_t)(mt * 16 + lr) * KVS + nt * 16 + q * 4] = uo;
      }
      ksacc[i] += loc;
    }
    // kv-step: wave reads its own k1 rows (no barrier needed)
#pragma unroll
    for (int ks = 0; ks < 2; ++ks) {
      bf16x8 bv[4];
#pragma unroll
      for (int dt = 0; dt < 4; ++dt)
        bv[dt] = *(const bf16x8*)&Vt_lds[(dt * 16 + lr) * KVS + ks * 32 + q * 8];
#pragma unroll
      for (int i = 0; i < 5; ++i) {
        if (i >= mc) continue;
        bf16x8 a1 = *(const bf16x8*)&k1_lds[(size_t)((ms + i) * 16 + lr) * KVS + ks * 32 + q * 8];
#pragma unroll
        for (int dt = 0; dt < 4; ++dt)
          kvacc[i][dt] = __builtin_amdgcn_mfma_f32_16x16x32_bf16(a1, bv[dt], kvacc[i][dt], 0, 0, 0);
      }
    }
  }

  // write partials: kvpart[chunk][bh][d][288 m]
  const size_t cb = (size_t)(chunk * BH_ + bh) * 64;
#pragma unroll
  for (int i = 0; i < 5; ++i) {
    if (i >= mc) continue;
    const int mt = ms + i;
#pragma unroll
    for (int dt = 0; dt < 4; ++dt) {
      float4 v4;
      v4.x = kvacc[i][dt][0]; v4.y = kvacc[i][dt][1];
      v4.z = kvacc[i][dt][2]; v4.w = kvacc[i][dt][3];
      *(float4*)&kvpart[(cb + dt * 16 + lr) * M2 + mt * 16 + q * 4] = v4;
    }
    float s = ksacc[i];
    s += __shfl_xor(s, 16);
    s += __shfl_xor(s, 32);
    if (lane < 16)
      ksumpart[(size_t)(chunk * BH_ + bh) * M2 + mt * 16 + lane] = s;
  }
}

// ---------------- K4: reduce partials -> kvt_g bf16 [bh][64][288], ksum_g f32 ----
__global__ __launch_bounds__(256) void kv_reduce2(
    const float* __restrict__ kvpart, const float* __restrict__ ksumpart,
    unsigned short* __restrict__ kvt_g, float* __restrict__ ksum_g)
{
  const int KVN = BH_ * 64 * M2;
  const int KSN = BH_ * M2;
  int idx = blockIdx.x * 256 + threadIdx.x;
  if (idx < KVN) {
    int m = idx % M2;
    float s = 0.f;
    if (m < M_) {
#pragma unroll
      for (int c = 0; c < 8; ++c) s += kvpart[(size_t)c * KVN + idx];
    }
    kvt_g[idx] = f2bf(s);
  } else if (idx < KVN + KSN) {
    int j = idx - KVN;
    int m = j % M2;
    float s = 0.f;
    if (m < M_) {
#pragma unroll
      for (int c = 0; c < 8; ++c) s += ksumpart[(size_t)c * KSN + j];
    }
    ksum_g[j] = s;
  }
}

// ---------------- K5: MFMA q-features + PV + normalize ----------------
__global__ __launch_bounds__(256) void attn_mfma(
    const unsigned short* __restrict__ qkv, const unsigned short* __restrict__ Pbf,
    const unsigned short* __restrict__ kvt_g, const float* __restrict__ ksum_g,
    unsigned short* __restrict__ attn)
{
  __shared__ unsigned short q1_lds[64 * MP];
  __shared__ unsigned short kvt_lds[64 * MP];
  __shared__ float ksum_lds[M2];
  __shared__ float z_lds[64];
  const int tid = threadIdx.x;
  const int bh = blockIdx.x, qt = blockIdx.y;
  const int b = bh / H_, h = bh % H_;
  const int n0 = qt * 64;
  const int w = tid >> 6, lane = tid & 63;
  const int lr = lane & 15, q = lane >> 4;

  // stage kvt (64x288 bf16) -> [64][MP]
  {
    const unsigned short* src = kvt_g + (size_t)bh * 64 * M2;
#pragma unroll
    for (int i = 0; i < 9; ++i) {
      int chunk = i * 256 + tid;            // 2304 total
      int r = chunk / 36, c = (chunk % 36) * 8;
      *(int4*)&kvt_lds[r * MP + c] = *(const int4*)(src + r * M2 + c);
    }
    if (tid < 72)
      *(float4*)&ksum_lds[tid * 4] = *(const float4*)(ksum_g + (size_t)bh * M2 + tid * 4);
    if (tid < 64) {
      const int4 z4 = {0, 0, 0, 0};
      *(int4*)&q1_lds[tid * MP + 272] = z4;
      *(int4*)&q1_lds[tid * MP + 280] = z4;
    }
  }
  __syncthreads();

  // Q B-frags + diag (row n = w*16 + lr)
  const unsigned short* qrow = qkv + (size_t)(b * N_TOK + n0 + w * 16 + lr) * TC_ + h * HD_;
  bf16x8 bq0 = *(const bf16x8*)(qrow + q * 8);
  bf16x8 bq1 = *(const bf16x8*)(qrow + q * 8 + 32);
  float sq = 0.f;
  {
    const unsigned short* p0 = (const unsigned short*)&bq0;
    const unsigned short* p1 = (const unsigned short*)&bq1;
#pragma unroll
    for (int j = 0; j < 8; ++j) { float f = bf2f(p0[j]); sq = fmaf(f, f, sq); }
#pragma unroll
    for (int j = 0; j < 8; ++j) { float f = bf2f(p1[j]); sq = fmaf(f, f, sq); }
  }
  sq += __shfl_xor(sq, 16);
  sq += __shfl_xor(sq, 32);
  const float diag = 0.0625f * sq;

  // S: C[m][n], col = n = lane&15 (this wave's rows), row = m
  f32x4 sacc[17];
  const f32x4 fz = {0.f, 0.f, 0.f, 0.f};
#pragma unroll
  for (int mt = 0; mt < 17; ++mt) sacc[mt] = fz;
#pragma unroll
  for (int mt = 0; mt < 17; ++mt) {
    const unsigned short* prow = Pbf + (size_t)(mt * 16 + lr) * 64;
    bf16x8 ap0 = *(const bf16x8*)(prow + q * 8);
    bf16x8 ap1 = *(const bf16x8*)(prow + q * 8 + 32);
    sacc[mt] = __builtin_amdgcn_mfma_f32_16x16x32_bf16(ap0, bq0, sacc[mt], 0, 0, 0);
    sacc[mt] = __builtin_amdgcn_mfma_f32_16x16x32_bf16(ap1, bq1, sacc[mt], 0, 0, 0);
  }

  // row-max over m (raw scale), reduce across quarters
  float mxr = NEG_INF;
#pragma unroll
  for (int mt = 0; mt < 17; ++mt) {
#pragma unroll
    for (int j = 0; j < 4; ++j) {
      int m = mt * 16 + q * 4 + j;
      if (m < M_) mxr = fmaxf(mxr, sacc[mt][j]);
    }
  }
  mxr = fmaxf(mxr, __shfl_xor(mxr, 16));
  mxr = fmaxf(mxr, __shfl_xor(mxr, 32));
  const float mxd = DN * mxr;

  // q1 = RATIO*(exp(dash - diag - mx) + eps); pack bf16; zp
  float zp = 0.f;
#pragma unroll
  for (int mt = 0; mt < 17; ++mt) {
    ushort4 uo;
    unsigned short* puo = (unsigned short*)&uo;
#pragma unroll
    for (int j = 0; j < 4; ++j) {
      const int m = mt * 16 + q * 4 + j;
      float q1f = 0.f;
      if (m < M_) {
        float dash = DN * sacc[mt][j];
        q1f = RATIO * (__expf(dash - diag - mxd) + FEPS);
      }
      zp = fmaf(q1f, ksum_lds[m], zp);
      puo[j] = f2bf(q1f);
    }
    *(ushort4*)&q1_lds[(w * 16 + lr) * MP + mt * 16 + q * 4] = uo;
  }
  zp += __shfl_xor(zp, 16);
  zp += __shfl_xor(zp, 32);
  if (q == 0) z_lds[w * 16 + lr] = 1.0f / zp;

  // PV: out[n][d] = q1[n][m] x kv[m][d]; A = q1 rows (own), B = kvt rows (d)
  f32x4 oacc[4];
#pragma unroll
  for (int dt = 0; dt < 4; ++dt) oacc[dt] = fz;
#pragma unroll
  for (int ks = 0; ks < 9; ++ks) {
    bf16x8 aq = *(const bf16x8*)&q1_lds[(w * 16 + lr) * MP + ks * 32 + q * 8];
#pragma unroll
    for (int dt = 0; dt < 4; ++dt) {
      bf16x8 bkv = *(const bf16x8*)&kvt_lds[(dt * 16 + lr) * MP + ks * 32 + q * 8];
      oacc[dt] = __builtin_amdgcn_mfma_f32_16x16x32_bf16(aq, bkv, oacc[dt], 0, 0, 0);
    }
  }

  // epilogue: scale by z, write
  float zz[4];
#pragma unroll
  for (int j = 0; j < 4; ++j) zz[j] = z_lds[w * 16 + q * 4 + j];
#pragma unroll
  for (int dt = 0; dt < 4; ++dt) {
#pragma unroll
    for (int j = 0; j < 4; ++j) {
      const int r = b * N_TOK + n0 + w * 16 + q * 4 + j;
      attn[(size_t)r * C_ + h * HD_ + dt * 16 + lr] = f2bf(oacc[dt][j] * zz[j]);
    }
  }
}

extern "C" void kernel_launch(void* const* d_in, const int* in_sizes, int n_in,
                              void* d_out, int out_size, void* d_ws, size_t ws_size,
                              hipStream_t stream) {
  const float* x     = (const float*)d_in[0];
  const float* Wqkv  = (const float*)d_in[1];
  const float* Wproj = (const float*)d_in[2];
  const float* bproj = (const float*)d_in[3];
  const float* P     = (const float*)d_in[4];
  float* out = (float*)d_out;
  float* ws = (float*)d_ws;

  // ws layout (f32 words), total ~54.23M words = 217 MiB
  unsigned short* qkv    = (unsigned short*)ws;                 // [0, 37748736)
  // region Z (sequential reuse): xb -> kvpart -> attn
  unsigned short* xb     = (unsigned short*)(ws + 37748736);    // 12,582,912 w
  float*          kvpart = ws + 37748736;                       // 14,155,776 w
  unsigned short* attn   = (unsigned short*)(ws + 37748736);    // 12,582,912 w
  float* ksumpart = ws + 51904512;                              // 221,184 w
  unsigned short* kvt_g  = (unsigned short*)(ws + 52125696);    // 884,736 w
  float* ksum_g   = ws + 53010432;                              // 27,648 w
  float* bmax     = ws + 53038080;                              // 3,072 w
  float* kmaxp    = ws + 53041152;                              // 64 w
  unsigned short* Pbf    = (unsigned short*)(ws + 53041216);    // 9,216 w
  unsigned short* Wqkvt  = (unsigned short*)(ws + 53050432);    // 884,736 w
  unsigned short* Wprojt = (unsigned short*)(ws + 53935168);    // 294,912 w

  cast_bf16<<<dim3(24576), 256, 0, stream>>>(x, xb, ROWS_ * C_);
  transpose_cast<<<dim3(72, 24), 256, 0, stream>>>(Wqkv, Wqkvt, C_, TC_);
  transpose_cast<<<dim3(24, 24), 256, 0, stream>>>(Wproj, Wprojt, C_, C_);
  cast_pbf<<<dim3(72), 256, 0, stream>>>(P, Pbf);

  gemm_bf16<1, 0><<<dim3(18, 256), 256, 0, stream>>>(xb, Wqkvt, nullptr, qkv, ROWS_, TC_, C_);
  kmax_partial<<<dim3(3072), 320, 0, stream>>>(qkv, P, bmax);
  kmax_reduce<<<dim3(1), 256, 0, stream>>>(bmax, kmaxp, 3072);
  kv_partial_mfma<<<dim3(96, 8), 256, 0, stream>>>(qkv, Pbf, kmaxp, kvpart, ksumpart);
  kv_reduce2<<<dim3(7020), 256, 0, stream>>>(kvpart, ksumpart, kvt_g, ksum_g);
  attn_mfma<<<dim3(96, 64), 256, 0, stream>>>(qkv, Pbf, kvt_g, ksum_g, attn);
  gemm_bf16<0, 1><<<dim3(6, 256), 256, 0, stream>>>(attn, Wprojt, bproj, out, ROWS_, C_, C_);
}

// Round 6
// 599.537 us; speedup vs baseline: 8.3418x; 2.1447x over previous
//
#include <hip/hip_runtime.h>
#include <hip/hip_bf16.h>
#include <math.h>

#define B_ 8
#define N_TOK 4096
#define C_ 768
#define H_ 12
#define HD_ 64
#define M_ 266
#define TC_ 2304
#define BH_ 96
#define ROWS_ 32768

#define M2 288          // padded m-dim (9 ksteps x 32)
#define MP 296          // LDS m-stride (u16), 2-way-free banks
#define KVS 72          // LDS stride for K/Vt/k1 (u16)

#define DN 0.35355339059327373f      // 1/sqrt(sqrt(64))
#define RATIO 0.06131393394849658f   // 1/sqrt(266)
#define FEPS 1e-4f
#define NEG_INF -3.0e38f

typedef __attribute__((ext_vector_type(4))) float f32x4;
typedef __attribute__((ext_vector_type(8))) short bf16x8;

__device__ __forceinline__ float bf2f(unsigned short u) {
  return __uint_as_float(((unsigned int)u) << 16);
}
__device__ __forceinline__ unsigned short f2bf(float f) {
  unsigned int x = __float_as_uint(f);
  unsigned int r = (x + 0x7fffu + ((x >> 16) & 1u)) >> 16;
  return (unsigned short)r;
}

#define GLOAD_LDS16(g, l) \
  __builtin_amdgcn_global_load_lds( \
      (const __attribute__((address_space(1))) void*)(g), \
      (__attribute__((address_space(3))) void*)(l), 16, 0, 0)

// ---------------- prep: cast f32 -> bf16 elementwise ----------------
__global__ __launch_bounds__(256) void cast_bf16(
    const float* __restrict__ src, unsigned short* __restrict__ dst, int n)
{
  int i = (blockIdx.x * 256 + threadIdx.x) * 4;
  if (i < n) {
    float4 v = *(const float4*)&src[i];
    ushort4 u;
    u.x = f2bf(v.x); u.y = f2bf(v.y); u.z = f2bf(v.z); u.w = f2bf(v.w);
    *(ushort4*)&dst[i] = u;
  }
}

// ---------------- prep: P [266][64] f32 -> Pbf [288][64] bf16 (zero-padded) ----
__global__ __launch_bounds__(256) void cast_pbf(
    const float* __restrict__ P, unsigned short* __restrict__ Pbf)
{
  int idx = blockIdx.x * 256 + threadIdx.x;
  if (idx < M2 * 64) {
    int m = idx >> 6;
    Pbf[idx] = (m < M_) ? f2bf(P[idx]) : (unsigned short)0;
  }
}

// ---------------- prep: transpose + cast: src[R][Ccols] f32 -> dst[Ccols][R] bf16 ----
__global__ __launch_bounds__(256) void transpose_cast(
    const float* __restrict__ src, unsigned short* __restrict__ dst,
    int R, int Ccols)
{
  __shared__ float t[32][33];
  const int c0 = blockIdx.x * 32, r0 = blockIdx.y * 32;
  const int tx = threadIdx.x & 31, ty = threadIdx.x >> 5;
#pragma unroll
  for (int i = 0; i < 32; i += 8)
    t[ty + i][tx] = src[(size_t)(r0 + ty + i) * Ccols + c0 + tx];
  __syncthreads();
#pragma unroll
  for (int i = 0; i < 32; i += 8)
    dst[(size_t)(c0 + ty + i) * R + r0 + tx] = f2bf(t[tx][ty + i]);
}

// ---------------- MFMA GEMM: C[M,N] = A[M,K]bf16 x Bt[N,K]bf16 ----------------
template <int C_BF16, int HAS_BIAS>
__global__ __launch_bounds__(256) void gemm_bf16(
    const unsigned short* __restrict__ A, const unsigned short* __restrict__ Bt,
    const float* __restrict__ bias, void* __restrict__ Cptr,
    int Mdim, int Ndim, int Kdim)
{
  __shared__ unsigned short Asm[128 * 32];
  __shared__ unsigned short Bsm[128 * 32];
  const int tid = threadIdx.x;
  const int wid = tid >> 6, lane = tid & 63;
  const int row0 = blockIdx.y * 128, col0 = blockIdx.x * 128;
  const int wr = (wid >> 1) * 64, wc = (wid & 1) * 64;

  f32x4 acc[4][4];
  const f32x4 fz = {0.f, 0.f, 0.f, 0.f};
#pragma unroll
  for (int m = 0; m < 4; ++m)
#pragma unroll
    for (int n = 0; n < 4; ++n) acc[m][n] = fz;

  const unsigned short* agp = A + (size_t)(row0 + (wid << 5) + (lane >> 2)) * Kdim + ((lane & 3) << 3);
  const unsigned short* bgp = Bt + (size_t)(col0 + (wid << 5) + (lane >> 2)) * Kdim + ((lane & 3) << 3);
  unsigned short* alp = Asm + (wid << 10) + (lane << 3);
  unsigned short* blp = Bsm + (wid << 10) + (lane << 3);
  const size_t rstep = (size_t)16 * Kdim;

  const int fr = lane & 15;
  const int fk = (lane >> 4) << 3;

  for (int k0 = 0; k0 < Kdim; k0 += 32) {
    __syncthreads();
    GLOAD_LDS16(agp, alp);
    GLOAD_LDS16(agp + rstep, alp + 512);
    GLOAD_LDS16(bgp, blp);
    GLOAD_LDS16(bgp + rstep, blp + 512);
    agp += 32; bgp += 32;
    __syncthreads();
    bf16x8 av[4], bv[4];
#pragma unroll
    for (int m = 0; m < 4; ++m)
      av[m] = *(const bf16x8*)&Asm[(wr + m * 16 + fr) * 32 + fk];
#pragma unroll
    for (int n = 0; n < 4; ++n)
      bv[n] = *(const bf16x8*)&Bsm[(wc + n * 16 + fr) * 32 + fk];
#pragma unroll
    for (int m = 0; m < 4; ++m)
#pragma unroll
      for (int n = 0; n < 4; ++n)
        acc[m][n] = __builtin_amdgcn_mfma_f32_16x16x32_bf16(av[m], bv[n], acc[m][n], 0, 0, 0);
  }

  const int orow = (lane >> 4) << 2;
#pragma unroll
  for (int m = 0; m < 4; ++m) {
#pragma unroll
    for (int n = 0; n < 4; ++n) {
      const int c = col0 + wc + n * 16 + fr;
      float badd = 0.f;
      if constexpr (HAS_BIAS) badd = bias[c];
#pragma unroll
      for (int j = 0; j < 4; ++j) {
        const int r = row0 + wr + m * 16 + orow + j;
        float v = acc[m][n][j] + badd;
        if constexpr (C_BF16)
          ((unsigned short*)Cptr)[(size_t)r * Ndim + c] = f2bf(v);
        else
          ((float*)Cptr)[(size_t)r * Ndim + c] = v;
      }
    }
  }
}

// ---------------- K2: MFMA per-block max of key data_dash (raw dot) ----------
__global__ __launch_bounds__(256) void kmax_mfma(
    const unsigned short* __restrict__ qkv, const unsigned short* __restrict__ Pbf,
    float* __restrict__ bmax)
{
  __shared__ unsigned short K_lds[64 * KVS];
  __shared__ float red[4];
  const int tid = threadIdx.x;
  const int w = tid >> 6, lane = tid & 63;
  const int lr = lane & 15, q = lane >> 4;
  const int bh = blockIdx.x, chunk = blockIdx.y;
  const int b = bh / H_, h = bh % H_;
  const int ms = w * 4;
  const int mc = (w == 3) ? 5 : 4;
  const int sn = 16 * w + (lane >> 2);
  const int sd0 = (lane & 3) * 16;
  const f32x4 fz = {0.f, 0.f, 0.f, 0.f};
  float mx = NEG_INF;

  for (int g = 0; g < 8; ++g) {
    const int nb = chunk * 512 + g * 64;
    __syncthreads();
    {
      const unsigned short* kr = qkv + (size_t)(b * N_TOK + nb + sn) * TC_ + C_ + h * HD_ + sd0;
      *(int4*)&K_lds[sn * KVS + sd0] = *(const int4*)kr;
      *(int4*)&K_lds[sn * KVS + sd0 + 8] = *(const int4*)(kr + 8);
    }
    __syncthreads();
    bf16x8 bk[4][2];
#pragma unroll
    for (int nt = 0; nt < 4; ++nt)
#pragma unroll
      for (int ks = 0; ks < 2; ++ks)
        bk[nt][ks] = *(const bf16x8*)&K_lds[(nt * 16 + lr) * KVS + ks * 32 + q * 8];
#pragma unroll
    for (int i = 0; i < 5; ++i) {
      if (i >= mc) continue;
      const int mt = ms + i;
      const int m = mt * 16 + lr;
      const unsigned short* prow = Pbf + (size_t)m * 64;
      bf16x8 ap0 = *(const bf16x8*)(prow + q * 8);
      bf16x8 ap1 = *(const bf16x8*)(prow + q * 8 + 32);
#pragma unroll
      for (int nt = 0; nt < 4; ++nt) {
        f32x4 s = fz;
        s = __builtin_amdgcn_mfma_f32_16x16x32_bf16(bk[nt][0], ap0, s, 0, 0, 0);
        s = __builtin_amdgcn_mfma_f32_16x16x32_bf16(bk[nt][1], ap1, s, 0, 0, 0);
        if (m < M_)
          mx = fmaxf(mx, fmaxf(fmaxf(s[0], s[1]), fmaxf(s[2], s[3])));
      }
    }
  }
#pragma unroll
  for (int off = 32; off >= 1; off >>= 1) mx = fmaxf(mx, __shfl_xor(mx, off));
  if (lane == 0) red[w] = mx;
  __syncthreads();
  if (tid == 0)
    bmax[chunk * BH_ + bh] = fmaxf(fmaxf(red[0], red[1]), fmaxf(red[2], red[3]));
}

__global__ __launch_bounds__(256) void kmax_reduce(
    const float* __restrict__ bmax, float* __restrict__ kmaxp, int n)
{
  __shared__ float red[4];
  float v = NEG_INF;
  for (int i = threadIdx.x; i < n; i += 256) v = fmaxf(v, bmax[i]);
#pragma unroll
  for (int off = 32; off >= 1; off >>= 1) v = fmaxf(v, __shfl_xor(v, off));
  if ((threadIdx.x & 63) == 0) red[threadIdx.x >> 6] = v;
  __syncthreads();
  if (threadIdx.x == 0)
    kmaxp[0] = DN * fmaxf(fmaxf(red[0], red[1]), fmaxf(red[2], red[3]));
}

// ---------------- K3: MFMA k-features -> partial kv^T [64 d][288 m] + ksum ----
__global__ __launch_bounds__(256) void kv_partial_mfma(
    const unsigned short* __restrict__ qkv, const unsigned short* __restrict__ Pbf,
    const float* __restrict__ kmaxp,
    float* __restrict__ kvpart, float* __restrict__ ksumpart)
{
  __shared__ unsigned short K_lds[64 * KVS];
  __shared__ unsigned short Vt_lds[64 * KVS];
  __shared__ unsigned short k1_lds[272 * KVS];
  __shared__ float diag_lds[64];
  const int tid = threadIdx.x;
  const int w = tid >> 6, lane = tid & 63;
  const int lr = lane & 15, q = lane >> 4;
  const int bh = blockIdx.x, chunk = blockIdx.y;
  const int b = bh / H_, h = bh % H_;
  const float stab = kmaxp[0];
  const int ms = w * 4;                  // first mtile of this wave
  const int mc = (w == 3) ? 5 : 4;       // mtile count (17 total)

  f32x4 kvacc[5][4];
  float ksacc[5];
  const f32x4 fz = {0.f, 0.f, 0.f, 0.f};
#pragma unroll
  for (int i = 0; i < 5; ++i) {
    ksacc[i] = 0.f;
#pragma unroll
    for (int dt = 0; dt < 4; ++dt) kvacc[i][dt] = fz;
  }

  const int sn = 16 * w + (lane >> 2);
  const int sd0 = (lane & 3) * 16;

  for (int g = 0; g < 8; ++g) {
    const int nb = chunk * 512 + g * 64;
    __syncthreads();
    {
      const unsigned short* kr = qkv + (size_t)(b * N_TOK + nb + sn) * TC_ + C_ + h * HD_ + sd0;
      int4 k0 = *(const int4*)kr;
      int4 k1v = *(const int4*)(kr + 8);
      *(int4*)&K_lds[sn * KVS + sd0] = k0;
      *(int4*)&K_lds[sn * KVS + sd0 + 8] = k1v;
      const unsigned short* pk = (const unsigned short*)&k0;
      float sq = 0.f;
#pragma unroll
      for (int j = 0; j < 8; ++j) { float f = bf2f(pk[j]); sq = fmaf(f, f, sq); }
      const unsigned short* pk1 = (const unsigned short*)&k1v;
#pragma unroll
      for (int j = 0; j < 8; ++j) { float f = bf2f(pk1[j]); sq = fmaf(f, f, sq); }
      sq += __shfl_xor(sq, 1);
      sq += __shfl_xor(sq, 2);
      if ((lane & 3) == 0) diag_lds[sn] = 0.0625f * sq;
      const unsigned short* vr = kr + C_;
      int4 v0 = *(const int4*)vr;
      int4 v1 = *(const int4*)(vr + 8);
      const unsigned short* pv0 = (const unsigned short*)&v0;
      const unsigned short* pv1 = (const unsigned short*)&v1;
#pragma unroll
      for (int j = 0; j < 8; ++j) Vt_lds[(sd0 + j) * KVS + sn] = pv0[j];
#pragma unroll
      for (int j = 0; j < 8; ++j) Vt_lds[(sd0 + 8 + j) * KVS + sn] = pv1[j];
    }
    __syncthreads();

    bf16x8 bk[4][2];
#pragma unroll
    for (int nt = 0; nt < 4; ++nt)
#pragma unroll
      for (int ks = 0; ks < 2; ++ks)
        bk[nt][ks] = *(const bf16x8*)&K_lds[(nt * 16 + lr) * KVS + ks * 32 + q * 8];

#pragma unroll
    for (int i = 0; i < 5; ++i) {
      if (i >= mc) continue;
      const int mt = ms + i;
      const int m = mt * 16 + lr;
      const unsigned short* prow = Pbf + (size_t)m * 64;
      bf16x8 ap0 = *(const bf16x8*)(prow + q * 8);
      bf16x8 ap1 = *(const bf16x8*)(prow + q * 8 + 32);
      float loc = 0.f;
#pragma unroll
      for (int nt = 0; nt < 4; ++nt) {
        f32x4 s = fz;
        s = __builtin_amdgcn_mfma_f32_16x16x32_bf16(bk[nt][0], ap0, s, 0, 0, 0);
        s = __builtin_amdgcn_mfma_f32_16x16x32_bf16(bk[nt][1], ap1, s, 0, 0, 0);
        ushort4 uo;
        unsigned short* puo = (unsigned short*)&uo;
#pragma unroll
        for (int j = 0; j < 4; ++j) {
          const int nl = nt * 16 + q * 4 + j;
          float k1f = 0.f;
          if (m < M_) {
            float dash = DN * s[j];
            k1f = RATIO * (__expf(dash - diag_lds[nl] - stab) + FEPS);
          }
          loc += k1f;
          puo[j] = f2bf(k1f);
        }
        *(ushort4*)&k1_lds[(size_t)(mt * 16 + lr) * KVS + nt * 16 + q * 4] = uo;
      }
      ksacc[i] += loc;
    }
#pragma unroll
    for (int ks = 0; ks < 2; ++ks) {
      bf16x8 bv[4];
#pragma unroll
      for (int dt = 0; dt < 4; ++dt)
        bv[dt] = *(const bf16x8*)&Vt_lds[(dt * 16 + lr) * KVS + ks * 32 + q * 8];
#pragma unroll
      for (int i = 0; i < 5; ++i) {
        if (i >= mc) continue;
        bf16x8 a1 = *(const bf16x8*)&k1_lds[(size_t)((ms + i) * 16 + lr) * KVS + ks * 32 + q * 8];
#pragma unroll
        for (int dt = 0; dt < 4; ++dt)
          kvacc[i][dt] = __builtin_amdgcn_mfma_f32_16x16x32_bf16(a1, bv[dt], kvacc[i][dt], 0, 0, 0);
      }
    }
  }

  const size_t cb = (size_t)(chunk * BH_ + bh) * 64;
#pragma unroll
  for (int i = 0; i < 5; ++i) {
    if (i >= mc) continue;
    const int mt = ms + i;
#pragma unroll
    for (int dt = 0; dt < 4; ++dt) {
      float4 v4;
      v4.x = kvacc[i][dt][0]; v4.y = kvacc[i][dt][1];
      v4.z = kvacc[i][dt][2]; v4.w = kvacc[i][dt][3];
      *(float4*)&kvpart[(cb + dt * 16 + lr) * M2 + mt * 16 + q * 4] = v4;
    }
    float s = ksacc[i];
    s += __shfl_xor(s, 16);
    s += __shfl_xor(s, 32);
    if (lane < 16)
      ksumpart[(size_t)(chunk * BH_ + bh) * M2 + mt * 16 + lane] = s;
  }
}

// ---------------- K4: reduce partials -> kvt_g bf16 [bh][64][288], ksum_g f32 ----
__global__ __launch_bounds__(256) void kv_reduce2(
    const float* __restrict__ kvpart, const float* __restrict__ ksumpart,
    unsigned short* __restrict__ kvt_g, float* __restrict__ ksum_g)
{
  const int KVN = BH_ * 64 * M2;
  const int KSN = BH_ * M2;
  int idx = blockIdx.x * 256 + threadIdx.x;
  if (idx < KVN) {
    int m = idx % M2;
    float s = 0.f;
    if (m < M_) {
#pragma unroll
      for (int c = 0; c < 8; ++c) s += kvpart[(size_t)c * KVN + idx];
    }
    kvt_g[idx] = f2bf(s);
  } else if (idx < KVN + KSN) {
    int j = idx - KVN;
    int m = j % M2;
    float s = 0.f;
    if (m < M_) {
#pragma unroll
      for (int c = 0; c < 8; ++c) s += ksumpart[(size_t)c * KSN + j];
    }
    ksum_g[j] = s;
  }
}

// ---------------- K5: MFMA q-features + PV + normalize ----------------
__global__ __launch_bounds__(256) void attn_mfma(
    const unsigned short* __restrict__ qkv, const unsigned short* __restrict__ Pbf,
    const unsigned short* __restrict__ kvt_g, const float* __restrict__ ksum_g,
    unsigned short* __restrict__ attn)
{
  __shared__ unsigned short q1_lds[64 * MP];
  __shared__ unsigned short kvt_lds[64 * MP];
  __shared__ float ksum_lds[M2];
  __shared__ float z_lds[64];
  const int tid = threadIdx.x;
  const int bh = blockIdx.x, qt = blockIdx.y;
  const int b = bh / H_, h = bh % H_;
  const int n0 = qt * 64;
  const int w = tid >> 6, lane = tid & 63;
  const int lr = lane & 15, q = lane >> 4;

  {
    const unsigned short* src = kvt_g + (size_t)bh * 64 * M2;
#pragma unroll
    for (int i = 0; i < 9; ++i) {
      int chunk = i * 256 + tid;
      int r = chunk / 36, c = (chunk % 36) * 8;
      *(int4*)&kvt_lds[r * MP + c] = *(const int4*)(src + r * M2 + c);
    }
    if (tid < 72)
      *(float4*)&ksum_lds[tid * 4] = *(const float4*)(ksum_g + (size_t)bh * M2 + tid * 4);
    if (tid < 64) {
      const int4 z4 = {0, 0, 0, 0};
      *(int4*)&q1_lds[tid * MP + 272] = z4;
      *(int4*)&q1_lds[tid * MP + 280] = z4;
    }
  }
  __syncthreads();

  const unsigned short* qrow = qkv + (size_t)(b * N_TOK + n0 + w * 16 + lr) * TC_ + h * HD_;
  bf16x8 bq0 = *(const bf16x8*)(qrow + q * 8);
  bf16x8 bq1 = *(const bf16x8*)(qrow + q * 8 + 32);
  float sq = 0.f;
  {
    const unsigned short* p0 = (const unsigned short*)&bq0;
    const unsigned short* p1 = (const unsigned short*)&bq1;
#pragma unroll
    for (int j = 0; j < 8; ++j) { float f = bf2f(p0[j]); sq = fmaf(f, f, sq); }
#pragma unroll
    for (int j = 0; j < 8; ++j) { float f = bf2f(p1[j]); sq = fmaf(f, f, sq); }
  }
  sq += __shfl_xor(sq, 16);
  sq += __shfl_xor(sq, 32);
  const float diag = 0.0625f * sq;

  f32x4 sacc[17];
  const f32x4 fz = {0.f, 0.f, 0.f, 0.f};
#pragma unroll
  for (int mt = 0; mt < 17; ++mt) sacc[mt] = fz;
#pragma unroll
  for (int mt = 0; mt < 17; ++mt) {
    const unsigned short* prow = Pbf + (size_t)(mt * 16 + lr) * 64;
    bf16x8 ap0 = *(const bf16x8*)(prow + q * 8);
    bf16x8 ap1 = *(const bf16x8*)(prow + q * 8 + 32);
    sacc[mt] = __builtin_amdgcn_mfma_f32_16x16x32_bf16(ap0, bq0, sacc[mt], 0, 0, 0);
    sacc[mt] = __builtin_amdgcn_mfma_f32_16x16x32_bf16(ap1, bq1, sacc[mt], 0, 0, 0);
  }

  float mxr = NEG_INF;
#pragma unroll
  for (int mt = 0; mt < 17; ++mt) {
#pragma unroll
    for (int j = 0; j < 4; ++j) {
      int m = mt * 16 + q * 4 + j;
      if (m < M_) mxr = fmaxf(mxr, sacc[mt][j]);
    }
  }
  mxr = fmaxf(mxr, __shfl_xor(mxr, 16));
  mxr = fmaxf(mxr, __shfl_xor(mxr, 32));
  const float mxd = DN * mxr;

  float zp = 0.f;
#pragma unroll
  for (int mt = 0; mt < 17; ++mt) {
    ushort4 uo;
    unsigned short* puo = (unsigned short*)&uo;
#pragma unroll
    for (int j = 0; j < 4; ++j) {
      const int m = mt * 16 + q * 4 + j;
      float q1f = 0.f;
      if (m < M_) {
        float dash = DN * sacc[mt][j];
        q1f = RATIO * (__expf(dash - diag - mxd) + FEPS);
      }
      zp = fmaf(q1f, ksum_lds[m], zp);
      puo[j] = f2bf(q1f);
    }
    *(ushort4*)&q1_lds[(w * 16 + lr) * MP + mt * 16 + q * 4] = uo;
  }
  zp += __shfl_xor(zp, 16);
  zp += __shfl_xor(zp, 32);
  if (q == 0) z_lds[w * 16 + lr] = 1.0f / zp;

  f32x4 oacc[4];
#pragma unroll
  for (int dt = 0; dt < 4; ++dt) oacc[dt] = fz;
#pragma unroll
  for (int ks = 0; ks < 9; ++ks) {
    bf16x8 aq = *(const bf16x8*)&q1_lds[(w * 16 + lr) * MP + ks * 32 + q * 8];
#pragma unroll
    for (int dt = 0; dt < 4; ++dt) {
      bf16x8 bkv = *(const bf16x8*)&kvt_lds[(dt * 16 + lr) * MP + ks * 32 + q * 8];
      oacc[dt] = __builtin_amdgcn_mfma_f32_16x16x32_bf16(aq, bkv, oacc[dt], 0, 0, 0);
    }
  }

  float zz[4];
#pragma unroll
  for (int j = 0; j < 4; ++j) zz[j] = z_lds[w * 16 + q * 4 + j];
#pragma unroll
  for (int dt = 0; dt < 4; ++dt) {
#pragma unroll
    for (int j = 0; j < 4; ++j) {
      const int r = b * N_TOK + n0 + w * 16 + q * 4 + j;
      attn[(size_t)r * C_ + h * HD_ + dt * 16 + lr] = f2bf(oacc[dt][j] * zz[j]);
    }
  }
}

extern "C" void kernel_launch(void* const* d_in, const int* in_sizes, int n_in,
                              void* d_out, int out_size, void* d_ws, size_t ws_size,
                              hipStream_t stream) {
  const float* x     = (const float*)d_in[0];
  const float* Wqkv  = (const float*)d_in[1];
  const float* Wproj = (const float*)d_in[2];
  const float* bproj = (const float*)d_in[3];
  const float* P     = (const float*)d_in[4];
  float* out = (float*)d_out;
  float* ws = (float*)d_ws;

  // ws layout (f32 words), total ~54.23M words = 217 MiB
  unsigned short* qkv    = (unsigned short*)ws;                 // [0, 37748736)
  unsigned short* xb     = (unsigned short*)(ws + 37748736);    // 12,582,912 w
  float*          kvpart = ws + 37748736;                       // 14,155,776 w
  unsigned short* attn   = (unsigned short*)(ws + 37748736);    // 12,582,912 w
  float* ksumpart = ws + 51904512;                              // 221,184 w
  unsigned short* kvt_g  = (unsigned short*)(ws + 52125696);    // 884,736 w
  float* ksum_g   = ws + 53010432;                              // 27,648 w
  float* bmax     = ws + 53038080;                              // 3,072 w
  float* kmaxp    = ws + 53041152;                              // 64 w
  unsigned short* Pbf    = (unsigned short*)(ws + 53041216);    // 9,216 w
  unsigned short* Wqkvt  = (unsigned short*)(ws + 53050432);    // 884,736 w
  unsigned short* Wprojt = (unsigned short*)(ws + 53935168);    // 294,912 w

  cast_bf16<<<dim3(24576), 256, 0, stream>>>(x, xb, ROWS_ * C_);
  transpose_cast<<<dim3(72, 24), 256, 0, stream>>>(Wqkv, Wqkvt, C_, TC_);
  transpose_cast<<<dim3(24, 24), 256, 0, stream>>>(Wproj, Wprojt, C_, C_);
  cast_pbf<<<dim3(72), 256, 0, stream>>>(P, Pbf);

  gemm_bf16<1, 0><<<dim3(18, 256), 256, 0, stream>>>(xb, Wqkvt, nullptr, qkv, ROWS_, TC_, C_);
  kmax_mfma<<<dim3(96, 8), 256, 0, stream>>>(qkv, Pbf, bmax);
  kmax_reduce<<<dim3(1), 256, 0, stream>>>(bmax, kmaxp, 768);
  kv_partial_mfma<<<dim3(96, 8), 256, 0, stream>>>(qkv, Pbf, kmaxp, kvpart, ksumpart);
  kv_reduce2<<<dim3(7020), 256, 0, stream>>>(kvpart, ksumpart, kvt_g, ksum_g);
  attn_mfma<<<dim3(96, 64), 256, 0, stream>>>(qkv, Pbf, kvt_g, ksum_g, attn);
  gemm_bf16<0, 1><<<dim3(6, 256), 256, 0, stream>>>(attn, Wprojt, bproj, out, ROWS_, C_, C_);
}

// Round 7
// 582.291 us; speedup vs baseline: 8.5889x; 1.0296x over previous
//
#include <hip/hip_runtime.h>
#include <hip/hip_bf16.h>
#include <math.h>

#define B_ 8
#define N_TOK 4096
#define C_ 768
#define H_ 12
#define HD_ 64
#define M_ 266
#define TC_ 2304
#define BH_ 96
#define ROWS_ 32768

#define M2 288          // padded m-dim (9 ksteps x 32)
#define MP 296          // LDS m-stride (u16), 2-way-free banks
#define KVS 72          // LDS stride for K/Vt/k1 (u16)

#define DN 0.35355339059327373f      // 1/sqrt(sqrt(64))
#define RATIO 0.06131393394849658f   // 1/sqrt(266)
#define FEPS 1e-4f
#define NEG_INF -3.0e38f

typedef __attribute__((ext_vector_type(4))) float f32x4;
typedef __attribute__((ext_vector_type(8))) short bf16x8;

__device__ __forceinline__ float bf2f(unsigned short u) {
  return __uint_as_float(((unsigned int)u) << 16);
}
__device__ __forceinline__ unsigned short f2bf(float f) {
  unsigned int x = __float_as_uint(f);
  unsigned int r = (x + 0x7fffu + ((x >> 16) & 1u)) >> 16;
  return (unsigned short)r;
}

#define GLOAD_LDS16(g, l) \
  __builtin_amdgcn_global_load_lds( \
      (const __attribute__((address_space(1))) void*)(g), \
      (__attribute__((address_space(3))) void*)(l), 16, 0, 0)

// ---------------- prep: cast f32 -> bf16 elementwise ----------------
__global__ __launch_bounds__(256) void cast_bf16(
    const float* __restrict__ src, unsigned short* __restrict__ dst, int n)
{
  int i = (blockIdx.x * 256 + threadIdx.x) * 4;
  if (i < n) {
    float4 v = *(const float4*)&src[i];
    ushort4 u;
    u.x = f2bf(v.x); u.y = f2bf(v.y); u.z = f2bf(v.z); u.w = f2bf(v.w);
    *(ushort4*)&dst[i] = u;
  }
}

// ---------------- prep: P [266][64] f32 -> Pbf [288][64] bf16 (zero-padded) ----
__global__ __launch_bounds__(256) void cast_pbf(
    const float* __restrict__ P, unsigned short* __restrict__ Pbf)
{
  int idx = blockIdx.x * 256 + threadIdx.x;
  if (idx < M2 * 64) {
    int m = idx >> 6;
    Pbf[idx] = (m < M_) ? f2bf(P[idx]) : (unsigned short)0;
  }
}

// ---------------- prep: transpose + cast: src[R][Ccols] f32 -> dst[Ccols][R] bf16 ----
__global__ __launch_bounds__(256) void transpose_cast(
    const float* __restrict__ src, unsigned short* __restrict__ dst,
    int R, int Ccols)
{
  __shared__ float t[32][33];
  const int c0 = blockIdx.x * 32, r0 = blockIdx.y * 32;
  const int tx = threadIdx.x & 31, ty = threadIdx.x >> 5;
#pragma unroll
  for (int i = 0; i < 32; i += 8)
    t[ty + i][tx] = src[(size_t)(r0 + ty + i) * Ccols + c0 + tx];
  __syncthreads();
#pragma unroll
  for (int i = 0; i < 32; i += 8)
    dst[(size_t)(c0 + ty + i) * R + r0 + tx] = f2bf(t[tx][ty + i]);
}

// ====== deep-pipelined GEMM for QKV: C[M,2304]bf16 = A[M,768] x Bt[2304,768] ======
// BM=256 BN=128 BK=64; 8 waves (2Mx4N); 3 LDS buffers, stage-distance 2;
// counted vmcnt (12/6/0), raw s_barrier, st_16x32 swizzle, setprio, XCD swizzle.
__global__ __launch_bounds__(512) void gemm_qkv256(
    const unsigned short* __restrict__ A, const unsigned short* __restrict__ Bt,
    unsigned short* __restrict__ Cptr)
{
  __shared__ unsigned short lds_[73728];   // 3 x (A 16384 + B 8192) u16 = 144 KiB
  const int Kdim = 768, Ndim = TC_;
  const int tid = threadIdx.x;
  const int lane = tid & 63, w = tid >> 6;

  // XCD-aware block swizzle (2304 % 8 == 0)
  const int id = blockIdx.x;
  const int sid = (id & 7) * 288 + (id >> 3);
  const int row0 = (sid / 18) * 256;
  const int col0 = (sid % 18) * 128;

  // ---- staging constants (inverse-swizzled global source, linear LDS dest) ----
  const int l3 = lane >> 3;
  const int srow = w * 8 + l3;                                  // + c*64
  const int skb = ((lane & 7) * 16) ^ (((lane >> 5) & 1) << 5); // byte col in row
  const size_t agb0 = (size_t)(row0 + srow) * Kdim + (skb >> 1);
  const size_t agb1 = (size_t)(row0 + 64 + srow) * Kdim + (skb >> 1);
  const size_t agb2 = (size_t)(row0 + 128 + srow) * Kdim + (skb >> 1);
  const size_t agb3 = (size_t)(row0 + 192 + srow) * Kdim + (skb >> 1);
  const size_t bgb0 = (size_t)(col0 + srow) * Kdim + (skb >> 1);
  const size_t bgb1 = (size_t)(col0 + 64 + srow) * Kdim + (skb >> 1);
  const int al0 = 0 * 4096 + w * 512 + lane * 8;
  const int al1 = 1 * 4096 + w * 512 + lane * 8;
  const int al2 = 2 * 4096 + w * 512 + lane * 8;
  const int al3 = 3 * 4096 + w * 512 + lane * 8;
  const int bl0 = 16384 + 0 * 4096 + w * 512 + lane * 8;
  const int bl1 = 16384 + 1 * 4096 + w * 512 + lane * 8;

#define STAGE_Q(tt) do { \
    unsigned short* Lq_ = lds_ + ((tt) % 3) * 24576; \
    const int kq_ = (tt) * 64; \
    GLOAD_LDS16(A + agb0 + kq_, Lq_ + al0); \
    GLOAD_LDS16(A + agb1 + kq_, Lq_ + al1); \
    GLOAD_LDS16(A + agb2 + kq_, Lq_ + al2); \
    GLOAD_LDS16(A + agb3 + kq_, Lq_ + al3); \
    GLOAD_LDS16(Bt + bgb0 + kq_, Lq_ + bl0); \
    GLOAD_LDS16(Bt + bgb1 + kq_, Lq_ + bl1); \
  } while (0)

  // ---- fragment-read constants (swizzled read) ----
  const int fr = lane & 15, q = lane >> 4;
  const int wm = w >> 2, wn = w & 3;
  const int sconst = ((fr >> 2) & 1) << 5;   // byte-bit5 XOR, constant per thread
  const int abase_r = ((((wm * 128 + fr) * 128) + q * 16) ^ sconst) >> 1;           // u16
  const int bbase_r = 16384 + (((((wn * 32 + fr) * 128) + q * 16) ^ sconst) >> 1);  // u16

  f32x4 acc[8][2];
  const f32x4 fz = {0.f, 0.f, 0.f, 0.f};
#pragma unroll
  for (int m = 0; m < 8; ++m) { acc[m][0] = fz; acc[m][1] = fz; }

  STAGE_Q(0);
  STAGE_Q(1);

#pragma unroll 1
  for (int t = 0; t < 12; ++t) {
    if (t < 10) STAGE_Q(t + 2);
    if (t < 10)       asm volatile("s_waitcnt vmcnt(12)" ::: "memory");
    else if (t == 10) asm volatile("s_waitcnt vmcnt(6)" ::: "memory");
    else              asm volatile("s_waitcnt vmcnt(0)" ::: "memory");
    __builtin_amdgcn_sched_barrier(0);
    __builtin_amdgcn_s_barrier();
    __builtin_amdgcn_sched_barrier(0);

    const unsigned short* Lb = lds_ + (t % 3) * 24576;
#pragma unroll
    for (int ks = 0; ks < 2; ++ks) {
      bf16x8 bv0 = *(const bf16x8*)&Lb[bbase_r + ks * 32];
      bf16x8 bv1 = *(const bf16x8*)&Lb[bbase_r + 1024 + ks * 32];
      bf16x8 av[8];
#pragma unroll
      for (int m = 0; m < 8; ++m)
        av[m] = *(const bf16x8*)&Lb[abase_r + m * 1024 + ks * 32];
      __builtin_amdgcn_s_setprio(1);
#pragma unroll
      for (int m = 0; m < 8; ++m) {
        acc[m][0] = __builtin_amdgcn_mfma_f32_16x16x32_bf16(av[m], bv0, acc[m][0], 0, 0, 0);
        acc[m][1] = __builtin_amdgcn_mfma_f32_16x16x32_bf16(av[m], bv1, acc[m][1], 0, 0, 0);
      }
      __builtin_amdgcn_s_setprio(0);
    }
    __builtin_amdgcn_sched_barrier(0);
    __builtin_amdgcn_s_barrier();
    __builtin_amdgcn_sched_barrier(0);
  }
#undef STAGE_Q

  const int orow = q * 4;
#pragma unroll
  for (int m = 0; m < 8; ++m) {
#pragma unroll
    for (int n = 0; n < 2; ++n) {
      const int c = col0 + wn * 32 + n * 16 + fr;
#pragma unroll
      for (int j = 0; j < 4; ++j) {
        const int r = row0 + wm * 128 + m * 16 + orow + j;
        Cptr[(size_t)r * Ndim + c] = f2bf(acc[m][n][j]);
      }
    }
  }
}

// ---------------- MFMA GEMM (m97 128x128): C = A[M,K]bf16 x Bt[N,K]bf16 --------
template <int C_BF16, int HAS_BIAS>
__global__ __launch_bounds__(256) void gemm_bf16(
    const unsigned short* __restrict__ A, const unsigned short* __restrict__ Bt,
    const float* __restrict__ bias, void* __restrict__ Cptr,
    int Mdim, int Ndim, int Kdim)
{
  __shared__ unsigned short Asm[128 * 32];
  __shared__ unsigned short Bsm[128 * 32];
  const int tid = threadIdx.x;
  const int wid = tid >> 6, lane = tid & 63;
  const int row0 = blockIdx.y * 128, col0 = blockIdx.x * 128;
  const int wr = (wid >> 1) * 64, wc = (wid & 1) * 64;

  f32x4 acc[4][4];
  const f32x4 fz = {0.f, 0.f, 0.f, 0.f};
#pragma unroll
  for (int m = 0; m < 4; ++m)
#pragma unroll
    for (int n = 0; n < 4; ++n) acc[m][n] = fz;

  const unsigned short* agp = A + (size_t)(row0 + (wid << 5) + (lane >> 2)) * Kdim + ((lane & 3) << 3);
  const unsigned short* bgp = Bt + (size_t)(col0 + (wid << 5) + (lane >> 2)) * Kdim + ((lane & 3) << 3);
  unsigned short* alp = Asm + (wid << 10) + (lane << 3);
  unsigned short* blp = Bsm + (wid << 10) + (lane << 3);
  const size_t rstep = (size_t)16 * Kdim;

  const int fr = lane & 15;
  const int fk = (lane >> 4) << 3;

  for (int k0 = 0; k0 < Kdim; k0 += 32) {
    __syncthreads();
    GLOAD_LDS16(agp, alp);
    GLOAD_LDS16(agp + rstep, alp + 512);
    GLOAD_LDS16(bgp, blp);
    GLOAD_LDS16(bgp + rstep, blp + 512);
    agp += 32; bgp += 32;
    __syncthreads();
    bf16x8 av[4], bv[4];
#pragma unroll
    for (int m = 0; m < 4; ++m)
      av[m] = *(const bf16x8*)&Asm[(wr + m * 16 + fr) * 32 + fk];
#pragma unroll
    for (int n = 0; n < 4; ++n)
      bv[n] = *(const bf16x8*)&Bsm[(wc + n * 16 + fr) * 32 + fk];
#pragma unroll
    for (int m = 0; m < 4; ++m)
#pragma unroll
      for (int n = 0; n < 4; ++n)
        acc[m][n] = __builtin_amdgcn_mfma_f32_16x16x32_bf16(av[m], bv[n], acc[m][n], 0, 0, 0);
  }

  const int orow = (lane >> 4) << 2;
#pragma unroll
  for (int m = 0; m < 4; ++m) {
#pragma unroll
    for (int n = 0; n < 4; ++n) {
      const int c = col0 + wc + n * 16 + fr;
      float badd = 0.f;
      if constexpr (HAS_BIAS) badd = bias[c];
#pragma unroll
      for (int j = 0; j < 4; ++j) {
        const int r = row0 + wr + m * 16 + orow + j;
        float v = acc[m][n][j] + badd;
        if constexpr (C_BF16)
          ((unsigned short*)Cptr)[(size_t)r * Ndim + c] = f2bf(v);
        else
          ((float*)Cptr)[(size_t)r * Ndim + c] = v;
      }
    }
  }
}

// ---------------- K2: MFMA per-block max of key data_dash (raw dot) ----------
__global__ __launch_bounds__(256) void kmax_mfma(
    const unsigned short* __restrict__ qkv, const unsigned short* __restrict__ Pbf,
    float* __restrict__ bmax)
{
  __shared__ unsigned short K_lds[64 * KVS];
  __shared__ float red[4];
  const int tid = threadIdx.x;
  const int w = tid >> 6, lane = tid & 63;
  const int lr = lane & 15, q = lane >> 4;
  const int bh = blockIdx.x, chunk = blockIdx.y;
  const int b = bh / H_, h = bh % H_;
  const int ms = w * 4;
  const int mc = (w == 3) ? 5 : 4;
  const int sn = 16 * w + (lane >> 2);
  const int sd0 = (lane & 3) * 16;
  const f32x4 fz = {0.f, 0.f, 0.f, 0.f};
  float mx = NEG_INF;

  for (int g = 0; g < 8; ++g) {
    const int nb = chunk * 512 + g * 64;
    __syncthreads();
    {
      const unsigned short* kr = qkv + (size_t)(b * N_TOK + nb + sn) * TC_ + C_ + h * HD_ + sd0;
      *(int4*)&K_lds[sn * KVS + sd0] = *(const int4*)kr;
      *(int4*)&K_lds[sn * KVS + sd0 + 8] = *(const int4*)(kr + 8);
    }
    __syncthreads();
    bf16x8 bk[4][2];
#pragma unroll
    for (int nt = 0; nt < 4; ++nt)
#pragma unroll
      for (int ks = 0; ks < 2; ++ks)
        bk[nt][ks] = *(const bf16x8*)&K_lds[(nt * 16 + lr) * KVS + ks * 32 + q * 8];
#pragma unroll
    for (int i = 0; i < 5; ++i) {
      if (i >= mc) continue;
      const int mt = ms + i;
      const int m = mt * 16 + lr;
      const unsigned short* prow = Pbf + (size_t)m * 64;
      bf16x8 ap0 = *(const bf16x8*)(prow + q * 8);
      bf16x8 ap1 = *(const bf16x8*)(prow + q * 8 + 32);
#pragma unroll
      for (int nt = 0; nt < 4; ++nt) {
        f32x4 s = fz;
        s = __builtin_amdgcn_mfma_f32_16x16x32_bf16(bk[nt][0], ap0, s, 0, 0, 0);
        s = __builtin_amdgcn_mfma_f32_16x16x32_bf16(bk[nt][1], ap1, s, 0, 0, 0);
        if (m < M_)
          mx = fmaxf(mx, fmaxf(fmaxf(s[0], s[1]), fmaxf(s[2], s[3])));
      }
    }
  }
#pragma unroll
  for (int off = 32; off >= 1; off >>= 1) mx = fmaxf(mx, __shfl_xor(mx, off));
  if (lane == 0) red[w] = mx;
  __syncthreads();
  if (tid == 0)
    bmax[chunk * BH_ + bh] = fmaxf(fmaxf(red[0], red[1]), fmaxf(red[2], red[3]));
}

__global__ __launch_bounds__(256) void kmax_reduce(
    const float* __restrict__ bmax, float* __restrict__ kmaxp, int n)
{
  __shared__ float red[4];
  float v = NEG_INF;
  for (int i = threadIdx.x; i < n; i += 256) v = fmaxf(v, bmax[i]);
#pragma unroll
  for (int off = 32; off >= 1; off >>= 1) v = fmaxf(v, __shfl_xor(v, off));
  if ((threadIdx.x & 63) == 0) red[threadIdx.x >> 6] = v;
  __syncthreads();
  if (threadIdx.x == 0)
    kmaxp[0] = DN * fmaxf(fmaxf(red[0], red[1]), fmaxf(red[2], red[3]));
}

// ---------------- K3: MFMA k-features -> partial kv^T [64 d][288 m] + ksum ----
__global__ __launch_bounds__(256) void kv_partial_mfma(
    const unsigned short* __restrict__ qkv, const unsigned short* __restrict__ Pbf,
    const float* __restrict__ kmaxp,
    float* __restrict__ kvpart, float* __restrict__ ksumpart)
{
  __shared__ unsigned short K_lds[64 * KVS];
  __shared__ unsigned short Vt_lds[64 * KVS];
  __shared__ unsigned short k1_lds[272 * KVS];
  __shared__ float diag_lds[64];
  const int tid = threadIdx.x;
  const int w = tid >> 6, lane = tid & 63;
  const int lr = lane & 15, q = lane >> 4;
  const int bh = blockIdx.x, chunk = blockIdx.y;
  const int b = bh / H_, h = bh % H_;
  const float stab = kmaxp[0];
  const int ms = w * 4;
  const int mc = (w == 3) ? 5 : 4;

  f32x4 kvacc[5][4];
  float ksacc[5];
  const f32x4 fz = {0.f, 0.f, 0.f, 0.f};
#pragma unroll
  for (int i = 0; i < 5; ++i) {
    ksacc[i] = 0.f;
#pragma unroll
    for (int dt = 0; dt < 4; ++dt) kvacc[i][dt] = fz;
  }

  const int sn = 16 * w + (lane >> 2);
  const int sd0 = (lane & 3) * 16;

  for (int g = 0; g < 8; ++g) {
    const int nb = chunk * 512 + g * 64;
    __syncthreads();
    {
      const unsigned short* kr = qkv + (size_t)(b * N_TOK + nb + sn) * TC_ + C_ + h * HD_ + sd0;
      int4 k0 = *(const int4*)kr;
      int4 k1v = *(const int4*)(kr + 8);
      *(int4*)&K_lds[sn * KVS + sd0] = k0;
      *(int4*)&K_lds[sn * KVS + sd0 + 8] = k1v;
      const unsigned short* pk = (const unsigned short*)&k0;
      float sq = 0.f;
#pragma unroll
      for (int j = 0; j < 8; ++j) { float f = bf2f(pk[j]); sq = fmaf(f, f, sq); }
      const unsigned short* pk1 = (const unsigned short*)&k1v;
#pragma unroll
      for (int j = 0; j < 8; ++j) { float f = bf2f(pk1[j]); sq = fmaf(f, f, sq); }
      sq += __shfl_xor(sq, 1);
      sq += __shfl_xor(sq, 2);
      if ((lane & 3) == 0) diag_lds[sn] = 0.0625f * sq;
      const unsigned short* vr = kr + C_;
      int4 v0 = *(const int4*)vr;
      int4 v1 = *(const int4*)(vr + 8);
      const unsigned short* pv0 = (const unsigned short*)&v0;
      const unsigned short* pv1 = (const unsigned short*)&v1;
#pragma unroll
      for (int j = 0; j < 8; ++j) Vt_lds[(sd0 + j) * KVS + sn] = pv0[j];
#pragma unroll
      for (int j = 0; j < 8; ++j) Vt_lds[(sd0 + 8 + j) * KVS + sn] = pv1[j];
    }
    __syncthreads();

    bf16x8 bk[4][2];
#pragma unroll
    for (int nt = 0; nt < 4; ++nt)
#pragma unroll
      for (int ks = 0; ks < 2; ++ks)
        bk[nt][ks] = *(const bf16x8*)&K_lds[(nt * 16 + lr) * KVS + ks * 32 + q * 8];

#pragma unroll
    for (int i = 0; i < 5; ++i) {
      if (i >= mc) continue;
      const int mt = ms + i;
      const int m = mt * 16 + lr;
      const unsigned short* prow = Pbf + (size_t)m * 64;
      bf16x8 ap0 = *(const bf16x8*)(prow + q * 8);
      bf16x8 ap1 = *(const bf16x8*)(prow + q * 8 + 32);
      float loc = 0.f;
#pragma unroll
      for (int nt = 0; nt < 4; ++nt) {
        f32x4 s = fz;
        s = __builtin_amdgcn_mfma_f32_16x16x32_bf16(bk[nt][0], ap0, s, 0, 0, 0);
        s = __builtin_amdgcn_mfma_f32_16x16x32_bf16(bk[nt][1], ap1, s, 0, 0, 0);
        ushort4 uo;
        unsigned short* puo = (unsigned short*)&uo;
#pragma unroll
        for (int j = 0; j < 4; ++j) {
          const int nl = nt * 16 + q * 4 + j;
          float k1f = 0.f;
          if (m < M_) {
            float dash = DN * s[j];
            k1f = RATIO * (__expf(dash - diag_lds[nl] - stab) + FEPS);
          }
          loc += k1f;
          puo[j] = f2bf(k1f);
        }
        *(ushort4*)&k1_lds[(size_t)(mt * 16 + lr) * KVS + nt * 16 + q * 4] = uo;
      }
      ksacc[i] += loc;
    }
#pragma unroll
    for (int ks = 0; ks < 2; ++ks) {
      bf16x8 bv[4];
#pragma unroll
      for (int dt = 0; dt < 4; ++dt)
        bv[dt] = *(const bf16x8*)&Vt_lds[(dt * 16 + lr) * KVS + ks * 32 + q * 8];
#pragma unroll
      for (int i = 0; i < 5; ++i) {
        if (i >= mc) continue;
        bf16x8 a1 = *(const bf16x8*)&k1_lds[(size_t)((ms + i) * 16 + lr) * KVS + ks * 32 + q * 8];
#pragma unroll
        for (int dt = 0; dt < 4; ++dt)
          kvacc[i][dt] = __builtin_amdgcn_mfma_f32_16x16x32_bf16(a1, bv[dt], kvacc[i][dt], 0, 0, 0);
      }
    }
  }

  const size_t cb = (size_t)(chunk * BH_ + bh) * 64;
#pragma unroll
  for (int i = 0; i < 5; ++i) {
    if (i >= mc) continue;
    const int mt = ms + i;
#pragma unroll
    for (int dt = 0; dt < 4; ++dt) {
      float4 v4;
      v4.x = kvacc[i][dt][0]; v4.y = kvacc[i][dt][1];
      v4.z = kvacc[i][dt][2]; v4.w = kvacc[i][dt][3];
      *(float4*)&kvpart[(cb + dt * 16 + lr) * M2 + mt * 16 + q * 4] = v4;
    }
    float s = ksacc[i];
    s += __shfl_xor(s, 16);
    s += __shfl_xor(s, 32);
    if (lane < 16)
      ksumpart[(size_t)(chunk * BH_ + bh) * M2 + mt * 16 + lane] = s;
  }
}

// ---------------- K4: reduce partials -> kvt_g bf16 [bh][64][288], ksum_g f32 ----
__global__ __launch_bounds__(256) void kv_reduce2(
    const float* __restrict__ kvpart, const float* __restrict__ ksumpart,
    unsigned short* __restrict__ kvt_g, float* __restrict__ ksum_g)
{
  const int KVN = BH_ * 64 * M2;
  const int KSN = BH_ * M2;
  int idx = blockIdx.x * 256 + threadIdx.x;
  if (idx < KVN) {
    int m = idx % M2;
    float s = 0.f;
    if (m < M_) {
#pragma unroll
      for (int c = 0; c < 8; ++c) s += kvpart[(size_t)c * KVN + idx];
    }
    kvt_g[idx] = f2bf(s);
  } else if (idx < KVN + KSN) {
    int j = idx - KVN;
    int m = j % M2;
    float s = 0.f;
    if (m < M_) {
#pragma unroll
      for (int c = 0; c < 8; ++c) s += ksumpart[(size_t)c * KSN + j];
    }
    ksum_g[j] = s;
  }
}

// ---------------- K5: MFMA q-features + PV + normalize ----------------
__global__ __launch_bounds__(256) void attn_mfma(
    const unsigned short* __restrict__ qkv, const unsigned short* __restrict__ Pbf,
    const unsigned short* __restrict__ kvt_g, const float* __restrict__ ksum_g,
    unsigned short* __restrict__ attn)
{
  __shared__ unsigned short q1_lds[64 * MP];
  __shared__ unsigned short kvt_lds[64 * MP];
  __shared__ float ksum_lds[M2];
  __shared__ float z_lds[64];
  const int tid = threadIdx.x;
  const int bh = blockIdx.x, qt = blockIdx.y;
  const int b = bh / H_, h = bh % H_;
  const int n0 = qt * 64;
  const int w = tid >> 6, lane = tid & 63;
  const int lr = lane & 15, q = lane >> 4;

  {
    const unsigned short* src = kvt_g + (size_t)bh * 64 * M2;
#pragma unroll
    for (int i = 0; i < 9; ++i) {
      int chunk = i * 256 + tid;
      int r = chunk / 36, c = (chunk % 36) * 8;
      *(int4*)&kvt_lds[r * MP + c] = *(const int4*)(src + r * M2 + c);
    }
    if (tid < 72)
      *(float4*)&ksum_lds[tid * 4] = *(const float4*)(ksum_g + (size_t)bh * M2 + tid * 4);
    if (tid < 64) {
      const int4 z4 = {0, 0, 0, 0};
      *(int4*)&q1_lds[tid * MP + 272] = z4;
      *(int4*)&q1_lds[tid * MP + 280] = z4;
    }
  }
  __syncthreads();

  const unsigned short* qrow = qkv + (size_t)(b * N_TOK + n0 + w * 16 + lr) * TC_ + h * HD_;
  bf16x8 bq0 = *(const bf16x8*)(qrow + q * 8);
  bf16x8 bq1 = *(const bf16x8*)(qrow + q * 8 + 32);
  float sq = 0.f;
  {
    const unsigned short* p0 = (const unsigned short*)&bq0;
    const unsigned short* p1 = (const unsigned short*)&bq1;
#pragma unroll
    for (int j = 0; j < 8; ++j) { float f = bf2f(p0[j]); sq = fmaf(f, f, sq); }
#pragma unroll
    for (int j = 0; j < 8; ++j) { float f = bf2f(p1[j]); sq = fmaf(f, f, sq); }
  }
  sq += __shfl_xor(sq, 16);
  sq += __shfl_xor(sq, 32);
  const float diag = 0.0625f * sq;

  f32x4 sacc[17];
  const f32x4 fz = {0.f, 0.f, 0.f, 0.f};
#pragma unroll
  for (int mt = 0; mt < 17; ++mt) sacc[mt] = fz;
#pragma unroll
  for (int mt = 0; mt < 17; ++mt) {
    const unsigned short* prow = Pbf + (size_t)(mt * 16 + lr) * 64;
    bf16x8 ap0 = *(const bf16x8*)(prow + q * 8);
    bf16x8 ap1 = *(const bf16x8*)(prow + q * 8 + 32);
    sacc[mt] = __builtin_amdgcn_mfma_f32_16x16x32_bf16(ap0, bq0, sacc[mt], 0, 0, 0);
    sacc[mt] = __builtin_amdgcn_mfma_f32_16x16x32_bf16(ap1, bq1, sacc[mt], 0, 0, 0);
  }

  float mxr = NEG_INF;
#pragma unroll
  for (int mt = 0; mt < 17; ++mt) {
#pragma unroll
    for (int j = 0; j < 4; ++j) {
      int m = mt * 16 + q * 4 + j;
      if (m < M_) mxr = fmaxf(mxr, sacc[mt][j]);
    }
  }
  mxr = fmaxf(mxr, __shfl_xor(mxr, 16));
  mxr = fmaxf(mxr, __shfl_xor(mxr, 32));
  const float mxd = DN * mxr;

  float zp = 0.f;
#pragma unroll
  for (int mt = 0; mt < 17; ++mt) {
    ushort4 uo;
    unsigned short* puo = (unsigned short*)&uo;
#pragma unroll
    for (int j = 0; j < 4; ++j) {
      const int m = mt * 16 + q * 4 + j;
      float q1f = 0.f;
      if (m < M_) {
        float dash = DN * sacc[mt][j];
        q1f = RATIO * (__expf(dash - diag - mxd) + FEPS);
      }
      zp = fmaf(q1f, ksum_lds[m], zp);
      puo[j] = f2bf(q1f);
    }
    *(ushort4*)&q1_lds[(w * 16 + lr) * MP + mt * 16 + q * 4] = uo;
  }
  zp += __shfl_xor(zp, 16);
  zp += __shfl_xor(zp, 32);
  if (q == 0) z_lds[w * 16 + lr] = 1.0f / zp;

  f32x4 oacc[4];
#pragma unroll
  for (int dt = 0; dt < 4; ++dt) oacc[dt] = fz;
#pragma unroll
  for (int ks = 0; ks < 9; ++ks) {
    bf16x8 aq = *(const bf16x8*)&q1_lds[(w * 16 + lr) * MP + ks * 32 + q * 8];
#pragma unroll
    for (int dt = 0; dt < 4; ++dt) {
      bf16x8 bkv = *(const bf16x8*)&kvt_lds[(dt * 16 + lr) * MP + ks * 32 + q * 8];
      oacc[dt] = __builtin_amdgcn_mfma_f32_16x16x32_bf16(aq, bkv, oacc[dt], 0, 0, 0);
    }
  }

  float zz[4];
#pragma unroll
  for (int j = 0; j < 4; ++j) zz[j] = z_lds[w * 16 + q * 4 + j];
#pragma unroll
  for (int dt = 0; dt < 4; ++dt) {
#pragma unroll
    for (int j = 0; j < 4; ++j) {
      const int r = b * N_TOK + n0 + w * 16 + q * 4 + j;
      attn[(size_t)r * C_ + h * HD_ + dt * 16 + lr] = f2bf(oacc[dt][j] * zz[j]);
    }
  }
}

extern "C" void kernel_launch(void* const* d_in, const int* in_sizes, int n_in,
                              void* d_out, int out_size, void* d_ws, size_t ws_size,
                              hipStream_t stream) {
  const float* x     = (const float*)d_in[0];
  const float* Wqkv  = (const float*)d_in[1];
  const float* Wproj = (const float*)d_in[2];
  const float* bproj = (const float*)d_in[3];
  const float* P     = (const float*)d_in[4];
  float* out = (float*)d_out;
  float* ws = (float*)d_ws;

  // ws layout (f32 words), total ~54.23M words = 217 MiB
  unsigned short* qkv    = (unsigned short*)ws;                 // [0, 37748736)
  unsigned short* xb     = (unsigned short*)(ws + 37748736);    // 12,582,912 w
  float*          kvpart = ws + 37748736;                       // 14,155,776 w
  unsigned short* attn   = (unsigned short*)(ws + 37748736);    // 12,582,912 w
  float* ksumpart = ws + 51904512;                              // 221,184 w
  unsigned short* kvt_g  = (unsigned short*)(ws + 52125696);    // 884,736 w
  float* ksum_g   = ws + 53010432;                              // 27,648 w
  float* bmax     = ws + 53038080;                              // 3,072 w
  float* kmaxp    = ws + 53041152;                              // 64 w
  unsigned short* Pbf    = (unsigned short*)(ws + 53041216);    // 9,216 w
  unsigned short* Wqkvt  = (unsigned short*)(ws + 53050432);    // 884,736 w
  unsigned short* Wprojt = (unsigned short*)(ws + 53935168);    // 294,912 w

  cast_bf16<<<dim3(24576), 256, 0, stream>>>(x, xb, ROWS_ * C_);
  transpose_cast<<<dim3(72, 24), 256, 0, stream>>>(Wqkv, Wqkvt, C_, TC_);
  transpose_cast<<<dim3(24, 24), 256, 0, stream>>>(Wproj, Wprojt, C_, C_);
  cast_pbf<<<dim3(72), 256, 0, stream>>>(P, Pbf);

  gemm_qkv256<<<dim3(2304), 512, 0, stream>>>(xb, Wqkvt, qkv);
  kmax_mfma<<<dim3(96, 8), 256, 0, stream>>>(qkv, Pbf, bmax);
  kmax_reduce<<<dim3(1), 256, 0, stream>>>(bmax, kmaxp, 768);
  kv_partial_mfma<<<dim3(96, 8), 256, 0, stream>>>(qkv, Pbf, kmaxp, kvpart, ksumpart);
  kv_reduce2<<<dim3(7020), 256, 0, stream>>>(kvpart, ksumpart, kvt_g, ksum_g);
  attn_mfma<<<dim3(96, 64), 256, 0, stream>>>(qkv, Pbf, kvt_g, ksum_g, attn);
  gemm_bf16<0, 1><<<dim3(6, 256), 256, 0, stream>>>(attn, Wprojt, bproj, out, ROWS_, C_, C_);
}

// Round 8
// 576.254 us; speedup vs baseline: 8.6789x; 1.0105x over previous
//
#include <hip/hip_runtime.h>
#include <hip/hip_bf16.h>
#include <math.h>

#define B_ 8
#define N_TOK 4096
#define C_ 768
#define H_ 12
#define HD_ 64
#define M_ 266
#define TC_ 2304
#define BH_ 96
#define ROWS_ 32768

#define M2 288          // padded m-dim (9 ksteps x 32)
#define MP 296          // LDS m-stride (u16), 16B-aligned rows
#define KVS 72          // LDS stride for K/Vt/k1 (u16), 16B-aligned rows

#define DN 0.35355339059327373f      // 1/sqrt(sqrt(64))
#define RATIO 0.06131393394849658f   // 1/sqrt(266)
#define FEPS 1e-4f
#define NEG_INF -3.0e38f

typedef __attribute__((ext_vector_type(4))) float f32x4;
typedef __attribute__((ext_vector_type(8))) short bf16x8;

__device__ __forceinline__ float bf2f(unsigned short u) {
  return __uint_as_float(((unsigned int)u) << 16);
}
__device__ __forceinline__ unsigned short f2bf(float f) {
  unsigned int x = __float_as_uint(f);
  unsigned int r = (x + 0x7fffu + ((x >> 16) & 1u)) >> 16;
  return (unsigned short)r;
}

#define GLOAD_LDS16(g, l) \
  __builtin_amdgcn_global_load_lds( \
      (const __attribute__((address_space(1))) void*)(g), \
      (__attribute__((address_space(3))) void*)(l), 16, 0, 0)

// ---------------- prep: cast f32 -> bf16 elementwise ----------------
__global__ __launch_bounds__(256) void cast_bf16(
    const float* __restrict__ src, unsigned short* __restrict__ dst, int n)
{
  int i = (blockIdx.x * 256 + threadIdx.x) * 4;
  if (i < n) {
    float4 v = *(const float4*)&src[i];
    ushort4 u;
    u.x = f2bf(v.x); u.y = f2bf(v.y); u.z = f2bf(v.z); u.w = f2bf(v.w);
    *(ushort4*)&dst[i] = u;
  }
}

// ---------------- prep: P [266][64] f32 -> Pbf [288][64] bf16 (zero-padded) ----
__global__ __launch_bounds__(256) void cast_pbf(
    const float* __restrict__ P, unsigned short* __restrict__ Pbf)
{
  int idx = blockIdx.x * 256 + threadIdx.x;
  if (idx < M2 * 64) {
    int m = idx >> 6;
    Pbf[idx] = (m < M_) ? f2bf(P[idx]) : (unsigned short)0;
  }
}

// ---------------- prep: transpose + cast: src[R][Ccols] f32 -> dst[Ccols][R] bf16 ----
__global__ __launch_bounds__(256) void transpose_cast(
    const float* __restrict__ src, unsigned short* __restrict__ dst,
    int R, int Ccols)
{
  __shared__ float t[32][33];
  const int c0 = blockIdx.x * 32, r0 = blockIdx.y * 32;
  const int tx = threadIdx.x & 31, ty = threadIdx.x >> 5;
#pragma unroll
  for (int i = 0; i < 32; i += 8)
    t[ty + i][tx] = src[(size_t)(r0 + ty + i) * Ccols + c0 + tx];
  __syncthreads();
#pragma unroll
  for (int i = 0; i < 32; i += 8)
    dst[(size_t)(c0 + ty + i) * R + r0 + tx] = f2bf(t[tx][ty + i]);
}

// ====== deep-pipelined GEMM for QKV: C[M,2304]bf16 = A[M,768] x Bt[2304,768] ======
__global__ __launch_bounds__(512) void gemm_qkv256(
    const unsigned short* __restrict__ A, const unsigned short* __restrict__ Bt,
    unsigned short* __restrict__ Cptr)
{
  __shared__ unsigned short lds_[73728];   // 3 x (A 16384 + B 8192) u16 = 144 KiB
  const int Kdim = 768, Ndim = TC_;
  const int tid = threadIdx.x;
  const int lane = tid & 63, w = tid >> 6;

  const int id = blockIdx.x;
  const int sid = (id & 7) * 288 + (id >> 3);
  const int row0 = (sid / 18) * 256;
  const int col0 = (sid % 18) * 128;

  const int l3 = lane >> 3;
  const int srow = w * 8 + l3;
  const int skb = ((lane & 7) * 16) ^ (((lane >> 5) & 1) << 5);
  const size_t agb0 = (size_t)(row0 + srow) * Kdim + (skb >> 1);
  const size_t agb1 = (size_t)(row0 + 64 + srow) * Kdim + (skb >> 1);
  const size_t agb2 = (size_t)(row0 + 128 + srow) * Kdim + (skb >> 1);
  const size_t agb3 = (size_t)(row0 + 192 + srow) * Kdim + (skb >> 1);
  const size_t bgb0 = (size_t)(col0 + srow) * Kdim + (skb >> 1);
  const size_t bgb1 = (size_t)(col0 + 64 + srow) * Kdim + (skb >> 1);
  const int al0 = 0 * 4096 + w * 512 + lane * 8;
  const int al1 = 1 * 4096 + w * 512 + lane * 8;
  const int al2 = 2 * 4096 + w * 512 + lane * 8;
  const int al3 = 3 * 4096 + w * 512 + lane * 8;
  const int bl0 = 16384 + 0 * 4096 + w * 512 + lane * 8;
  const int bl1 = 16384 + 1 * 4096 + w * 512 + lane * 8;

#define STAGE_Q(tt) do { \
    unsigned short* Lq_ = lds_ + ((tt) % 3) * 24576; \
    const int kq_ = (tt) * 64; \
    GLOAD_LDS16(A + agb0 + kq_, Lq_ + al0); \
    GLOAD_LDS16(A + agb1 + kq_, Lq_ + al1); \
    GLOAD_LDS16(A + agb2 + kq_, Lq_ + al2); \
    GLOAD_LDS16(A + agb3 + kq_, Lq_ + al3); \
    GLOAD_LDS16(Bt + bgb0 + kq_, Lq_ + bl0); \
    GLOAD_LDS16(Bt + bgb1 + kq_, Lq_ + bl1); \
  } while (0)

  const int fr = lane & 15, q = lane >> 4;
  const int wm = w >> 2, wn = w & 3;
  const int sconst = ((fr >> 2) & 1) << 5;
  const int abase_r = ((((wm * 128 + fr) * 128) + q * 16) ^ sconst) >> 1;
  const int bbase_r = 16384 + (((((wn * 32 + fr) * 128) + q * 16) ^ sconst) >> 1);

  f32x4 acc[8][2];
  const f32x4 fz = {0.f, 0.f, 0.f, 0.f};
#pragma unroll
  for (int m = 0; m < 8; ++m) { acc[m][0] = fz; acc[m][1] = fz; }

  STAGE_Q(0);
  STAGE_Q(1);

#pragma unroll 1
  for (int t = 0; t < 12; ++t) {
    if (t < 10) STAGE_Q(t + 2);
    if (t < 10)       asm volatile("s_waitcnt vmcnt(12)" ::: "memory");
    else if (t == 10) asm volatile("s_waitcnt vmcnt(6)" ::: "memory");
    else              asm volatile("s_waitcnt vmcnt(0)" ::: "memory");
    __builtin_amdgcn_sched_barrier(0);
    __builtin_amdgcn_s_barrier();
    __builtin_amdgcn_sched_barrier(0);

    const unsigned short* Lb = lds_ + (t % 3) * 24576;
#pragma unroll
    for (int ks = 0; ks < 2; ++ks) {
      bf16x8 bv0 = *(const bf16x8*)&Lb[bbase_r + ks * 32];
      bf16x8 bv1 = *(const bf16x8*)&Lb[bbase_r + 1024 + ks * 32];
      bf16x8 av[8];
#pragma unroll
      for (int m = 0; m < 8; ++m)
        av[m] = *(const bf16x8*)&Lb[abase_r + m * 1024 + ks * 32];
      __builtin_amdgcn_s_setprio(1);
#pragma unroll
      for (int m = 0; m < 8; ++m) {
        acc[m][0] = __builtin_amdgcn_mfma_f32_16x16x32_bf16(av[m], bv0, acc[m][0], 0, 0, 0);
        acc[m][1] = __builtin_amdgcn_mfma_f32_16x16x32_bf16(av[m], bv1, acc[m][1], 0, 0, 0);
      }
      __builtin_amdgcn_s_setprio(0);
    }
    __builtin_amdgcn_sched_barrier(0);
    __builtin_amdgcn_s_barrier();
    __builtin_amdgcn_sched_barrier(0);
  }
#undef STAGE_Q

  const int orow = q * 4;
#pragma unroll
  for (int m = 0; m < 8; ++m) {
#pragma unroll
    for (int n = 0; n < 2; ++n) {
      const int c = col0 + wn * 32 + n * 16 + fr;
#pragma unroll
      for (int j = 0; j < 4; ++j) {
        const int r = row0 + wm * 128 + m * 16 + orow + j;
        Cptr[(size_t)r * Ndim + c] = f2bf(acc[m][n][j]);
      }
    }
  }
}

// ---------------- MFMA GEMM (m97 128x128): C = A[M,K]bf16 x Bt[N,K]bf16 --------
template <int C_BF16, int HAS_BIAS>
__global__ __launch_bounds__(256) void gemm_bf16(
    const unsigned short* __restrict__ A, const unsigned short* __restrict__ Bt,
    const float* __restrict__ bias, void* __restrict__ Cptr,
    int Mdim, int Ndim, int Kdim)
{
  __shared__ unsigned short Asm[128 * 32];
  __shared__ unsigned short Bsm[128 * 32];
  const int tid = threadIdx.x;
  const int wid = tid >> 6, lane = tid & 63;
  const int row0 = blockIdx.y * 128, col0 = blockIdx.x * 128;
  const int wr = (wid >> 1) * 64, wc = (wid & 1) * 64;

  f32x4 acc[4][4];
  const f32x4 fz = {0.f, 0.f, 0.f, 0.f};
#pragma unroll
  for (int m = 0; m < 4; ++m)
#pragma unroll
    for (int n = 0; n < 4; ++n) acc[m][n] = fz;

  const unsigned short* agp = A + (size_t)(row0 + (wid << 5) + (lane >> 2)) * Kdim + ((lane & 3) << 3);
  const unsigned short* bgp = Bt + (size_t)(col0 + (wid << 5) + (lane >> 2)) * Kdim + ((lane & 3) << 3);
  unsigned short* alp = Asm + (wid << 10) + (lane << 3);
  unsigned short* blp = Bsm + (wid << 10) + (lane << 3);
  const size_t rstep = (size_t)16 * Kdim;

  const int fr = lane & 15;
  const int fk = (lane >> 4) << 3;

  for (int k0 = 0; k0 < Kdim; k0 += 32) {
    __syncthreads();
    GLOAD_LDS16(agp, alp);
    GLOAD_LDS16(agp + rstep, alp + 512);
    GLOAD_LDS16(bgp, blp);
    GLOAD_LDS16(bgp + rstep, blp + 512);
    agp += 32; bgp += 32;
    __syncthreads();
    bf16x8 av[4], bv[4];
#pragma unroll
    for (int m = 0; m < 4; ++m)
      av[m] = *(const bf16x8*)&Asm[(wr + m * 16 + fr) * 32 + fk];
#pragma unroll
    for (int n = 0; n < 4; ++n)
      bv[n] = *(const bf16x8*)&Bsm[(wc + n * 16 + fr) * 32 + fk];
#pragma unroll
    for (int m = 0; m < 4; ++m)
#pragma unroll
      for (int n = 0; n < 4; ++n)
        acc[m][n] = __builtin_amdgcn_mfma_f32_16x16x32_bf16(av[m], bv[n], acc[m][n], 0, 0, 0);
  }

  const int orow = (lane >> 4) << 2;
#pragma unroll
  for (int m = 0; m < 4; ++m) {
#pragma unroll
    for (int n = 0; n < 4; ++n) {
      const int c = col0 + wc + n * 16 + fr;
      float badd = 0.f;
      if constexpr (HAS_BIAS) badd = bias[c];
#pragma unroll
      for (int j = 0; j < 4; ++j) {
        const int r = row0 + wr + m * 16 + orow + j;
        float v = acc[m][n][j] + badd;
        if constexpr (C_BF16)
          ((unsigned short*)Cptr)[(size_t)r * Ndim + c] = f2bf(v);
        else
          ((float*)Cptr)[(size_t)r * Ndim + c] = v;
      }
    }
  }
}

// ---------------- K2: MFMA per-block max, pipelined (dbuf + reg prefetch) -----
__global__ __launch_bounds__(256) void kmax_mfma(
    const unsigned short* __restrict__ qkv, const unsigned short* __restrict__ Pbf,
    float* __restrict__ bmax)
{
  __shared__ unsigned short K_lds[2][64 * KVS];
  __shared__ float red[4];
  const int tid = threadIdx.x;
  const int w = tid >> 6, lane = tid & 63;
  const int lr = lane & 15, q = lane >> 4;
  const int bh = blockIdx.x, chunk = blockIdx.y;
  const int b = bh / H_, h = bh % H_;
  const int ms = w * 4;
  const int mc = (w == 3) ? 5 : 4;
  const int sn = 16 * w + (lane >> 2);
  const int sd0 = (lane & 3) * 16;
  const f32x4 fz = {0.f, 0.f, 0.f, 0.f};
  float mx = NEG_INF;

  // hoist P fragments (rows <= 271 < 288, always in-bounds)
  bf16x8 pf0[5], pf1[5];
#pragma unroll
  for (int i = 0; i < 5; ++i) {
    const unsigned short* prow = Pbf + (size_t)((ms + i) * 16 + lr) * 64 + q * 8;
    pf0[i] = *(const bf16x8*)prow;
    pf1[i] = *(const bf16x8*)(prow + 32);
  }

  const unsigned short* kbase = qkv + (size_t)(b * N_TOK + chunk * 512 + sn) * TC_ + C_ + h * HD_ + sd0;
  const size_t gstep = (size_t)64 * TC_;

  int4 ka = *(const int4*)kbase;
  int4 kb = *(const int4*)(kbase + 8);
  *(int4*)&K_lds[0][sn * KVS + sd0] = ka;
  *(int4*)&K_lds[0][sn * KVS + sd0 + 8] = kb;
  asm volatile("s_waitcnt lgkmcnt(0)" ::: "memory");
  __builtin_amdgcn_s_barrier();

#pragma unroll 1
  for (int g = 0; g < 8; ++g) {
    const unsigned short* Kc = K_lds[g & 1];
    if (g < 7) {
      const unsigned short* kr = kbase + (size_t)(g + 1) * gstep;
      ka = *(const int4*)kr;
      kb = *(const int4*)(kr + 8);
    }
    __builtin_amdgcn_sched_barrier(0);
    bf16x8 bk[4][2];
#pragma unroll
    for (int nt = 0; nt < 4; ++nt) {
      bk[nt][0] = *(const bf16x8*)&Kc[(nt * 16 + lr) * KVS + q * 8];
      bk[nt][1] = *(const bf16x8*)&Kc[(nt * 16 + lr) * KVS + 32 + q * 8];
    }
#pragma unroll
    for (int i = 0; i < 5; ++i) {
      if (i >= mc) continue;
      const int m = (ms + i) * 16 + lr;
#pragma unroll
      for (int nt = 0; nt < 4; ++nt) {
        f32x4 s = fz;
        s = __builtin_amdgcn_mfma_f32_16x16x32_bf16(bk[nt][0], pf0[i], s, 0, 0, 0);
        s = __builtin_amdgcn_mfma_f32_16x16x32_bf16(bk[nt][1], pf1[i], s, 0, 0, 0);
        if (m < M_)
          mx = fmaxf(mx, fmaxf(fmaxf(s[0], s[1]), fmaxf(s[2], s[3])));
      }
    }
    if (g < 7) {
      __builtin_amdgcn_sched_barrier(0);
      unsigned short* Kn = (unsigned short*)K_lds[(g & 1) ^ 1];
      *(int4*)&Kn[sn * KVS + sd0] = ka;
      *(int4*)&Kn[sn * KVS + sd0 + 8] = kb;
      asm volatile("s_waitcnt lgkmcnt(0)" ::: "memory");
      __builtin_amdgcn_sched_barrier(0);
      __builtin_amdgcn_s_barrier();
      __builtin_amdgcn_sched_barrier(0);
    }
  }
#pragma unroll
  for (int off = 32; off >= 1; off >>= 1) mx = fmaxf(mx, __shfl_xor(mx, off));
  if (lane == 0) red[w] = mx;
  __syncthreads();
  if (tid == 0)
    bmax[chunk * BH_ + bh] = fmaxf(fmaxf(red[0], red[1]), fmaxf(red[2], red[3]));
}

__global__ __launch_bounds__(256) void kmax_reduce(
    const float* __restrict__ bmax, float* __restrict__ kmaxp, int n)
{
  __shared__ float red[4];
  float v = NEG_INF;
  for (int i = threadIdx.x; i < n; i += 256) v = fmaxf(v, bmax[i]);
#pragma unroll
  for (int off = 32; off >= 1; off >>= 1) v = fmaxf(v, __shfl_xor(v, off));
  if ((threadIdx.x & 63) == 0) red[threadIdx.x >> 6] = v;
  __syncthreads();
  if (threadIdx.x == 0)
    kmaxp[0] = DN * fmaxf(fmaxf(red[0], red[1]), fmaxf(red[2], red[3]));
}

// ---------------- K3: MFMA k-features -> partial kv^T, pipelined --------------
__global__ __launch_bounds__(256) void kv_partial_mfma(
    const unsigned short* __restrict__ qkv, const unsigned short* __restrict__ Pbf,
    const float* __restrict__ kmaxp,
    float* __restrict__ kvpart, float* __restrict__ ksumpart)
{
  __shared__ unsigned short K_lds[2][64 * KVS];
  __shared__ unsigned short Vt_lds[2][64 * KVS];
  __shared__ unsigned short k1_lds[272 * KVS];
  __shared__ float diag_lds[2][64];
  const int tid = threadIdx.x;
  const int w = tid >> 6, lane = tid & 63;
  const int lr = lane & 15, q = lane >> 4;
  const int bh = blockIdx.x, chunk = blockIdx.y;
  const int b = bh / H_, h = bh % H_;
  const float stab = kmaxp[0];
  const int ms = w * 4;
  const int mc = (w == 3) ? 5 : 4;
  const int sn = 16 * w + (lane >> 2);
  const int sd0 = (lane & 3) * 16;
  const f32x4 fz = {0.f, 0.f, 0.f, 0.f};

  f32x4 kvacc[5][4];
  float ksacc[5];
#pragma unroll
  for (int i = 0; i < 5; ++i) {
    ksacc[i] = 0.f;
#pragma unroll
    for (int dt = 0; dt < 4; ++dt) kvacc[i][dt] = fz;
  }

  // hoist P fragments
  bf16x8 pf0[5], pf1[5];
#pragma unroll
  for (int i = 0; i < 5; ++i) {
    const unsigned short* prow = Pbf + (size_t)((ms + i) * 16 + lr) * 64 + q * 8;
    pf0[i] = *(const bf16x8*)prow;
    pf1[i] = *(const bf16x8*)(prow + 32);
  }

  const unsigned short* kbase = qkv + (size_t)(b * N_TOK + chunk * 512 + sn) * TC_ + C_ + h * HD_ + sd0;
  const size_t gstep = (size_t)64 * TC_;

  auto write_buf = [&](int bsel, int4 wka, int4 wkb, int4 wva, int4 wvb) {
    *(int4*)&K_lds[bsel][sn * KVS + sd0] = wka;
    *(int4*)&K_lds[bsel][sn * KVS + sd0 + 8] = wkb;
    float sq = 0.f;
    const unsigned short* pk0 = (const unsigned short*)&wka;
#pragma unroll
    for (int j = 0; j < 8; ++j) { float f = bf2f(pk0[j]); sq = fmaf(f, f, sq); }
    const unsigned short* pk1 = (const unsigned short*)&wkb;
#pragma unroll
    for (int j = 0; j < 8; ++j) { float f = bf2f(pk1[j]); sq = fmaf(f, f, sq); }
    sq += __shfl_xor(sq, 1);
    sq += __shfl_xor(sq, 2);
    if ((lane & 3) == 0) diag_lds[bsel][sn] = 0.0625f * sq;
    const unsigned short* pv0 = (const unsigned short*)&wva;
    const unsigned short* pv1 = (const unsigned short*)&wvb;
#pragma unroll
    for (int j = 0; j < 8; ++j) Vt_lds[bsel][(sd0 + j) * KVS + sn] = pv0[j];
#pragma unroll
    for (int j = 0; j < 8; ++j) Vt_lds[bsel][(sd0 + 8 + j) * KVS + sn] = pv1[j];
  };

  int4 ka = *(const int4*)kbase;
  int4 kb = *(const int4*)(kbase + 8);
  int4 va = *(const int4*)(kbase + C_);
  int4 vb = *(const int4*)(kbase + C_ + 8);
  write_buf(0, ka, kb, va, vb);
  asm volatile("s_waitcnt lgkmcnt(0)" ::: "memory");
  __builtin_amdgcn_s_barrier();

#pragma unroll 1
  for (int g = 0; g < 8; ++g) {
    const int cur = g & 1;
    const unsigned short* Kc = K_lds[cur];
    const unsigned short* Vc = Vt_lds[cur];
    const float* Dc = diag_lds[cur];
    if (g < 7) {
      const unsigned short* kr = kbase + (size_t)(g + 1) * gstep;
      ka = *(const int4*)kr;
      kb = *(const int4*)(kr + 8);
      va = *(const int4*)(kr + C_);
      vb = *(const int4*)(kr + C_ + 8);
    }
    __builtin_amdgcn_sched_barrier(0);

    bf16x8 bk[4][2];
#pragma unroll
    for (int nt = 0; nt < 4; ++nt) {
      bk[nt][0] = *(const bf16x8*)&Kc[(nt * 16 + lr) * KVS + q * 8];
      bk[nt][1] = *(const bf16x8*)&Kc[(nt * 16 + lr) * KVS + 32 + q * 8];
    }

#pragma unroll
    for (int i = 0; i < 5; ++i) {
      if (i >= mc) continue;
      const int mt = ms + i;
      const int m = mt * 16 + lr;
      float loc = 0.f;
#pragma unroll
      for (int nt = 0; nt < 4; ++nt) {
        f32x4 s = fz;
        s = __builtin_amdgcn_mfma_f32_16x16x32_bf16(bk[nt][0], pf0[i], s, 0, 0, 0);
        s = __builtin_amdgcn_mfma_f32_16x16x32_bf16(bk[nt][1], pf1[i], s, 0, 0, 0);
        ushort4 uo;
        unsigned short* puo = (unsigned short*)&uo;
#pragma unroll
        for (int j = 0; j < 4; ++j) {
          const int nl = nt * 16 + q * 4 + j;
          float k1f = 0.f;
          if (m < M_) {
            float dash = DN * s[j];
            k1f = RATIO * (__expf(dash - Dc[nl] - stab) + FEPS);
          }
          loc += k1f;
          puo[j] = f2bf(k1f);
        }
        *(ushort4*)&k1_lds[(size_t)(mt * 16 + lr) * KVS + nt * 16 + q * 4] = uo;
      }
      ksacc[i] += loc;
    }
#pragma unroll
    for (int ks = 0; ks < 2; ++ks) {
      bf16x8 bv[4];
#pragma unroll
      for (int dt = 0; dt < 4; ++dt)
        bv[dt] = *(const bf16x8*)&Vc[(dt * 16 + lr) * KVS + ks * 32 + q * 8];
#pragma unroll
      for (int i = 0; i < 5; ++i) {
        if (i >= mc) continue;
        bf16x8 a1 = *(const bf16x8*)&k1_lds[(size_t)((ms + i) * 16 + lr) * KVS + ks * 32 + q * 8];
#pragma unroll
        for (int dt = 0; dt < 4; ++dt)
          kvacc[i][dt] = __builtin_amdgcn_mfma_f32_16x16x32_bf16(a1, bv[dt], kvacc[i][dt], 0, 0, 0);
      }
    }

    if (g < 7) {
      __builtin_amdgcn_sched_barrier(0);
      write_buf(cur ^ 1, ka, kb, va, vb);
      asm volatile("s_waitcnt lgkmcnt(0)" ::: "memory");
      __builtin_amdgcn_sched_barrier(0);
      __builtin_amdgcn_s_barrier();
      __builtin_amdgcn_sched_barrier(0);
    }
  }

  const size_t cb = (size_t)(chunk * BH_ + bh) * 64;
#pragma unroll
  for (int i = 0; i < 5; ++i) {
    if (i >= mc) continue;
    const int mt = ms + i;
#pragma unroll
    for (int dt = 0; dt < 4; ++dt) {
      float4 v4;
      v4.x = kvacc[i][dt][0]; v4.y = kvacc[i][dt][1];
      v4.z = kvacc[i][dt][2]; v4.w = kvacc[i][dt][3];
      *(float4*)&kvpart[(cb + dt * 16 + lr) * M2 + mt * 16 + q * 4] = v4;
    }
    float s = ksacc[i];
    s += __shfl_xor(s, 16);
    s += __shfl_xor(s, 32);
    if (lane < 16)
      ksumpart[(size_t)(chunk * BH_ + bh) * M2 + mt * 16 + lane] = s;
  }
}

// ---------------- K4: reduce partials -> kvt_g bf16 [bh][64][288], ksum_g f32 ----
__global__ __launch_bounds__(256) void kv_reduce2(
    const float* __restrict__ kvpart, const float* __restrict__ ksumpart,
    unsigned short* __restrict__ kvt_g, float* __restrict__ ksum_g)
{
  const int KVN = BH_ * 64 * M2;
  const int KSN = BH_ * M2;
  int idx = blockIdx.x * 256 + threadIdx.x;
  if (idx < KVN) {
    int m = idx % M2;
    float s = 0.f;
    if (m < M_) {
#pragma unroll
      for (int c = 0; c < 8; ++c) s += kvpart[(size_t)c * KVN + idx];
    }
    kvt_g[idx] = f2bf(s);
  } else if (idx < KVN + KSN) {
    int j = idx - KVN;
    int m = j % M2;
    float s = 0.f;
    if (m < M_) {
#pragma unroll
      for (int c = 0; c < 8; ++c) s += ksumpart[(size_t)c * KSN + j];
    }
    ksum_g[j] = s;
  }
}

// ---------------- K5: MFMA q-features + PV + normalize ----------------
__global__ __launch_bounds__(256) void attn_mfma(
    const unsigned short* __restrict__ qkv, const unsigned short* __restrict__ Pbf,
    const unsigned short* __restrict__ kvt_g, const float* __restrict__ ksum_g,
    unsigned short* __restrict__ attn)
{
  __shared__ unsigned short q1_lds[64 * MP];
  __shared__ unsigned short kvt_lds[64 * MP];
  __shared__ float ksum_lds[M2];
  __shared__ float z_lds[64];
  const int tid = threadIdx.x;
  const int bh = blockIdx.x, qt = blockIdx.y;
  const int b = bh / H_, h = bh % H_;
  const int n0 = qt * 64;
  const int w = tid >> 6, lane = tid & 63;
  const int lr = lane & 15, q = lane >> 4;

  {
    const unsigned short* src = kvt_g + (size_t)bh * 64 * M2;
#pragma unroll
    for (int i = 0; i < 9; ++i) {
      int chunk = i * 256 + tid;
      int r = chunk / 36, c = (chunk % 36) * 8;
      *(int4*)&kvt_lds[r * MP + c] = *(const int4*)(src + r * M2 + c);
    }
    if (tid < 72)
      *(float4*)&ksum_lds[tid * 4] = *(const float4*)(ksum_g + (size_t)bh * M2 + tid * 4);
    if (tid < 64) {
      const int4 z4 = {0, 0, 0, 0};
      *(int4*)&q1_lds[tid * MP + 272] = z4;
      *(int4*)&q1_lds[tid * MP + 280] = z4;
    }
  }
  __syncthreads();

  const unsigned short* qrow = qkv + (size_t)(b * N_TOK + n0 + w * 16 + lr) * TC_ + h * HD_;
  bf16x8 bq0 = *(const bf16x8*)(qrow + q * 8);
  bf16x8 bq1 = *(const bf16x8*)(qrow + q * 8 + 32);
  float sq = 0.f;
  {
    const unsigned short* p0 = (const unsigned short*)&bq0;
    const unsigned short* p1 = (const unsigned short*)&bq1;
#pragma unroll
    for (int j = 0; j < 8; ++j) { float f = bf2f(p0[j]); sq = fmaf(f, f, sq); }
#pragma unroll
    for (int j = 0; j < 8; ++j) { float f = bf2f(p1[j]); sq = fmaf(f, f, sq); }
  }
  sq += __shfl_xor(sq, 16);
  sq += __shfl_xor(sq, 32);
  const float diag = 0.0625f * sq;

  f32x4 sacc[17];
  const f32x4 fz = {0.f, 0.f, 0.f, 0.f};
#pragma unroll
  for (int mt = 0; mt < 17; ++mt) sacc[mt] = fz;
#pragma unroll
  for (int mt = 0; mt < 17; ++mt) {
    const unsigned short* prow = Pbf + (size_t)(mt * 16 + lr) * 64;
    bf16x8 ap0 = *(const bf16x8*)(prow + q * 8);
    bf16x8 ap1 = *(const bf16x8*)(prow + q * 8 + 32);
    sacc[mt] = __builtin_amdgcn_mfma_f32_16x16x32_bf16(ap0, bq0, sacc[mt], 0, 0, 0);
    sacc[mt] = __builtin_amdgcn_mfma_f32_16x16x32_bf16(ap1, bq1, sacc[mt], 0, 0, 0);
  }

  float mxr = NEG_INF;
#pragma unroll
  for (int mt = 0; mt < 17; ++mt) {
#pragma unroll
    for (int j = 0; j < 4; ++j) {
      int m = mt * 16 + q * 4 + j;
      if (m < M_) mxr = fmaxf(mxr, sacc[mt][j]);
    }
  }
  mxr = fmaxf(mxr, __shfl_xor(mxr, 16));
  mxr = fmaxf(mxr, __shfl_xor(mxr, 32));
  const float mxd = DN * mxr;

  float zp = 0.f;
#pragma unroll
  for (int mt = 0; mt < 17; ++mt) {
    ushort4 uo;
    unsigned short* puo = (unsigned short*)&uo;
#pragma unroll
    for (int j = 0; j < 4; ++j) {
      const int m = mt * 16 + q * 4 + j;
      float q1f = 0.f;
      if (m < M_) {
        float dash = DN * sacc[mt][j];
        q1f = RATIO * (__expf(dash - diag - mxd) + FEPS);
      }
      zp = fmaf(q1f, ksum_lds[m], zp);
      puo[j] = f2bf(q1f);
    }
    *(ushort4*)&q1_lds[(w * 16 + lr) * MP + mt * 16 + q * 4] = uo;
  }
  zp += __shfl_xor(zp, 16);
  zp += __shfl_xor(zp, 32);
  if (q == 0) z_lds[w * 16 + lr] = 1.0f / zp;

  f32x4 oacc[4];
#pragma unroll
  for (int dt = 0; dt < 4; ++dt) oacc[dt] = fz;
#pragma unroll
  for (int ks = 0; ks < 9; ++ks) {
    bf16x8 aq = *(const bf16x8*)&q1_lds[(w * 16 + lr) * MP + ks * 32 + q * 8];
#pragma unroll
    for (int dt = 0; dt < 4; ++dt) {
      bf16x8 bkv = *(const bf16x8*)&kvt_lds[(dt * 16 + lr) * MP + ks * 32 + q * 8];
      oacc[dt] = __builtin_amdgcn_mfma_f32_16x16x32_bf16(aq, bkv, oacc[dt], 0, 0, 0);
    }
  }

  float zz[4];
#pragma unroll
  for (int j = 0; j < 4; ++j) zz[j] = z_lds[w * 16 + q * 4 + j];
#pragma unroll
  for (int dt = 0; dt < 4; ++dt) {
#pragma unroll
    for (int j = 0; j < 4; ++j) {
      const int r = b * N_TOK + n0 + w * 16 + q * 4 + j;
      attn[(size_t)r * C_ + h * HD_ + dt * 16 + lr] = f2bf(oacc[dt][j] * zz[j]);
    }
  }
}

extern "C" void kernel_launch(void* const* d_in, const int* in_sizes, int n_in,
                              void* d_out, int out_size, void* d_ws, size_t ws_size,
                              hipStream_t stream) {
  const float* x     = (const float*)d_in[0];
  const float* Wqkv  = (const float*)d_in[1];
  const float* Wproj = (const float*)d_in[2];
  const float* bproj = (const float*)d_in[3];
  const float* P     = (const float*)d_in[4];
  float* out = (float*)d_out;
  float* ws = (float*)d_ws;

  // ws layout (f32 words), total ~54.23M words = 217 MiB
  unsigned short* qkv    = (unsigned short*)ws;                 // [0, 37748736)
  unsigned short* xb     = (unsigned short*)(ws + 37748736);    // 12,582,912 w
  float*          kvpart = ws + 37748736;                       // 14,155,776 w
  unsigned short* attn   = (unsigned short*)(ws + 37748736);    // 12,582,912 w
  float* ksumpart = ws + 51904512;                              // 221,184 w
  unsigned short* kvt_g  = (unsigned short*)(ws + 52125696);    // 884,736 w
  float* ksum_g   = ws + 53010432;                              // 27,648 w
  float* bmax     = ws + 53038080;                              // 3,072 w
  float* kmaxp    = ws + 53041152;                              // 64 w
  unsigned short* Pbf    = (unsigned short*)(ws + 53041216);    // 9,216 w
  unsigned short* Wqkvt  = (unsigned short*)(ws + 53050432);    // 884,736 w
  unsigned short* Wprojt = (unsigned short*)(ws + 53935168);    // 294,912 w

  cast_bf16<<<dim3(24576), 256, 0, stream>>>(x, xb, ROWS_ * C_);
  transpose_cast<<<dim3(72, 24), 256, 0, stream>>>(Wqkv, Wqkvt, C_, TC_);
  transpose_cast<<<dim3(24, 24), 256, 0, stream>>>(Wproj, Wprojt, C_, C_);
  cast_pbf<<<dim3(72), 256, 0, stream>>>(P, Pbf);

  gemm_qkv256<<<dim3(2304), 512, 0, stream>>>(xb, Wqkvt, qkv);
  kmax_mfma<<<dim3(96, 8), 256, 0, stream>>>(qkv, Pbf, bmax);
  kmax_reduce<<<dim3(1), 256, 0, stream>>>(bmax, kmaxp, 768);
  kv_partial_mfma<<<dim3(96, 8), 256, 0, stream>>>(qkv, Pbf, kmaxp, kvpart, ksumpart);
  kv_reduce2<<<dim3(7020), 256, 0, stream>>>(kvpart, ksumpart, kvt_g, ksum_g);
  attn_mfma<<<dim3(96, 64), 256, 0, stream>>>(qkv, Pbf, kvt_g, ksum_g, attn);
  gemm_bf16<0, 1><<<dim3(6, 256), 256, 0, stream>>>(attn, Wprojt, bproj, out, ROWS_, C_, C_);
}

// Round 9
// 557.750 us; speedup vs baseline: 8.9668x; 1.0332x over previous
//
#include <hip/hip_runtime.h>
#include <hip/hip_bf16.h>
#include <math.h>

#define B_ 8
#define N_TOK 4096
#define C_ 768
#define H_ 12
#define HD_ 64
#define M_ 266
#define TC_ 2304
#define BH_ 96
#define ROWS_ 32768

#define M2 288          // padded m-dim (9 ksteps x 32)
#define MP 296          // LDS m-stride (u16), 16B-aligned rows
#define KVS 72          // LDS stride for K/Vt/k1 (u16), 16B-aligned rows

#define DN 0.35355339059327373f      // 1/sqrt(sqrt(64))
#define RATIO 0.06131393394849658f   // 1/sqrt(266)
#define FEPS 1e-4f
#define NEG_INF -3.0e38f

typedef __attribute__((ext_vector_type(4))) float f32x4;
typedef __attribute__((ext_vector_type(8))) short bf16x8;

__device__ __forceinline__ float bf2f(unsigned short u) {
  return __uint_as_float(((unsigned int)u) << 16);
}
__device__ __forceinline__ unsigned short f2bf(float f) {
  unsigned int x = __float_as_uint(f);
  unsigned int r = (x + 0x7fffu + ((x >> 16) & 1u)) >> 16;
  return (unsigned short)r;
}

#define GLOAD_LDS16(g, l) \
  __builtin_amdgcn_global_load_lds( \
      (const __attribute__((address_space(1))) void*)(g), \
      (__attribute__((address_space(3))) void*)(l), 16, 0, 0)

// ---------------- prep: cast f32 -> bf16 elementwise ----------------
__global__ __launch_bounds__(256) void cast_bf16(
    const float* __restrict__ src, unsigned short* __restrict__ dst, int n)
{
  int i = (blockIdx.x * 256 + threadIdx.x) * 4;
  if (i < n) {
    float4 v = *(const float4*)&src[i];
    ushort4 u;
    u.x = f2bf(v.x); u.y = f2bf(v.y); u.z = f2bf(v.z); u.w = f2bf(v.w);
    *(ushort4*)&dst[i] = u;
  }
}

// ---------------- prep: P [266][64] f32 -> Pbf [288][64] bf16 (zero-padded) ----
__global__ __launch_bounds__(256) void cast_pbf(
    const float* __restrict__ P, unsigned short* __restrict__ Pbf)
{
  int idx = blockIdx.x * 256 + threadIdx.x;
  if (idx < M2 * 64) {
    int m = idx >> 6;
    Pbf[idx] = (m < M_) ? f2bf(P[idx]) : (unsigned short)0;
  }
}

// ---------------- prep: transpose + cast: src[R][Ccols] f32 -> dst[Ccols][R] bf16 ----
__global__ __launch_bounds__(256) void transpose_cast(
    const float* __restrict__ src, unsigned short* __restrict__ dst,
    int R, int Ccols)
{
  __shared__ float t[32][33];
  const int c0 = blockIdx.x * 32, r0 = blockIdx.y * 32;
  const int tx = threadIdx.x & 31, ty = threadIdx.x >> 5;
#pragma unroll
  for (int i = 0; i < 32; i += 8)
    t[ty + i][tx] = src[(size_t)(r0 + ty + i) * Ccols + c0 + tx];
  __syncthreads();
#pragma unroll
  for (int i = 0; i < 32; i += 8)
    dst[(size_t)(c0 + ty + i) * R + r0 + tx] = f2bf(t[tx][ty + i]);
}

// ====== deep-pipelined GEMM: C[M, NT*128] = A[M,768]bf16 x Bt[NT*128,768]bf16 ======
// BM=256 BN=128 BK=64; 8 waves (2Mx4N); 3 LDS buffers, stage distance 2;
// counted vmcnt; raw s_barrier; 3-bit XOR swizzle byte^=(row&7)<<4; setprio; XCD swizzle.
template <int NT, int C_BF16, int HAS_BIAS>
__global__ __launch_bounds__(512) void gemm_pipe(
    const unsigned short* __restrict__ A, const unsigned short* __restrict__ Bt,
    const float* __restrict__ bias, void* __restrict__ Cptr)
{
  __shared__ unsigned short lds_[73728];   // 3 x (A 16384 + B 8192) u16 = 144 KiB
  const int Kdim = 768, Ndim = NT * 128;
  const int tid = threadIdx.x;
  const int lane = tid & 63, w = tid >> 6;

  // XCD-aware block swizzle (grid = 128*NT, divisible by 8)
  const int id = blockIdx.x;
  const int sid = (id & 7) * (16 * NT) + (id >> 3);
  const int row0 = (sid / NT) * 256;
  const int col0 = (sid % NT) * 128;

  // ---- staging: linear LDS dest, inverse-swizzled global source ----
  // dest row (within 64-row tile chunk) = w*8 + (lane>>3); dest col-byte = (lane&7)*16
  // source col-byte = dest col-byte ^ ((row&7)<<4), row&7 = lane>>3
  const int srow = w * 8 + (lane >> 3);
  const int skb = (((lane & 7) ^ ((lane >> 3) & 7)) << 4);   // byte; /2 -> u16
  const size_t agb0 = (size_t)(row0 + srow) * Kdim + (skb >> 1);
  const size_t agb1 = (size_t)(row0 + 64 + srow) * Kdim + (skb >> 1);
  const size_t agb2 = (size_t)(row0 + 128 + srow) * Kdim + (skb >> 1);
  const size_t agb3 = (size_t)(row0 + 192 + srow) * Kdim + (skb >> 1);
  const size_t bgb0 = (size_t)(col0 + srow) * Kdim + (skb >> 1);
  const size_t bgb1 = (size_t)(col0 + 64 + srow) * Kdim + (skb >> 1);
  const int al0 = 0 * 4096 + w * 512 + lane * 8;
  const int al1 = 1 * 4096 + w * 512 + lane * 8;
  const int al2 = 2 * 4096 + w * 512 + lane * 8;
  const int al3 = 3 * 4096 + w * 512 + lane * 8;
  const int bl0 = 16384 + 0 * 4096 + w * 512 + lane * 8;
  const int bl1 = 16384 + 1 * 4096 + w * 512 + lane * 8;

#define STAGE_Q(tt) do { \
    unsigned short* Lq_ = lds_ + ((tt) % 3) * 24576; \
    const int kq_ = (tt) * 64; \
    GLOAD_LDS16(A + agb0 + kq_, Lq_ + al0); \
    GLOAD_LDS16(A + agb1 + kq_, Lq_ + al1); \
    GLOAD_LDS16(A + agb2 + kq_, Lq_ + al2); \
    GLOAD_LDS16(A + agb3 + kq_, Lq_ + al3); \
    GLOAD_LDS16(Bt + bgb0 + kq_, Lq_ + bl0); \
    GLOAD_LDS16(Bt + bgb1 + kq_, Lq_ + bl1); \
  } while (0)

  // ---- fragment-read constants (swizzled read) ----
  // logical (row, colbyte=16*(q+4*ks)) lives at colbyte ^ ((row&7)<<4); row&7 = fr&7
  const int fr = lane & 15, q = lane >> 4;
  const int wm = w >> 2, wn = w & 3;
  const int f7 = fr & 7;
  const int sl0 = ((q + 0) ^ f7) << 3;       // u16 col offset, ks=0
  const int sl1 = ((q + 4) ^ f7) << 3;       // u16 col offset, ks=1
  const int abase = (wm * 128 + fr) * 64;            // u16; + m*1024
  const int bbase0 = 16384 + (wn * 32 + fr) * 64;    // n=0 row
  const int bbase1 = 16384 + (wn * 32 + 16 + fr) * 64;

  f32x4 acc[8][2];
  const f32x4 fz = {0.f, 0.f, 0.f, 0.f};
#pragma unroll
  for (int m = 0; m < 8; ++m) { acc[m][0] = fz; acc[m][1] = fz; }

  STAGE_Q(0);
  STAGE_Q(1);

#pragma unroll 1
  for (int t = 0; t < 12; ++t) {
    if (t < 10) STAGE_Q(t + 2);
    if (t < 10)       asm volatile("s_waitcnt vmcnt(12)" ::: "memory");
    else if (t == 10) asm volatile("s_waitcnt vmcnt(6)" ::: "memory");
    else              asm volatile("s_waitcnt vmcnt(0)" ::: "memory");
    __builtin_amdgcn_sched_barrier(0);
    __builtin_amdgcn_s_barrier();
    __builtin_amdgcn_sched_barrier(0);

    const unsigned short* Lb = lds_ + (t % 3) * 24576;
#pragma unroll
    for (int ks = 0; ks < 2; ++ks) {
      const int sl = ks ? sl1 : sl0;
      bf16x8 bv0 = *(const bf16x8*)&Lb[bbase0 + sl];
      bf16x8 bv1 = *(const bf16x8*)&Lb[bbase1 + sl];
      bf16x8 av[8];
#pragma unroll
      for (int m = 0; m < 8; ++m)
        av[m] = *(const bf16x8*)&Lb[abase + m * 1024 + sl];
      __builtin_amdgcn_s_setprio(1);
#pragma unroll
      for (int m = 0; m < 8; ++m) {
        acc[m][0] = __builtin_amdgcn_mfma_f32_16x16x32_bf16(av[m], bv0, acc[m][0], 0, 0, 0);
        acc[m][1] = __builtin_amdgcn_mfma_f32_16x16x32_bf16(av[m], bv1, acc[m][1], 0, 0, 0);
      }
      __builtin_amdgcn_s_setprio(0);
    }
    __builtin_amdgcn_sched_barrier(0);
    __builtin_amdgcn_s_barrier();
    __builtin_amdgcn_sched_barrier(0);
  }
#undef STAGE_Q

  const int orow = q * 4;
#pragma unroll
  for (int m = 0; m < 8; ++m) {
#pragma unroll
    for (int n = 0; n < 2; ++n) {
      const int c = col0 + wn * 32 + n * 16 + fr;
      float badd = 0.f;
      if constexpr (HAS_BIAS) badd = bias[c];
#pragma unroll
      for (int j = 0; j < 4; ++j) {
        const int r = row0 + wm * 128 + m * 16 + orow + j;
        float v = acc[m][n][j] + badd;
        if constexpr (C_BF16)
          ((unsigned short*)Cptr)[(size_t)r * Ndim + c] = f2bf(v);
        else
          ((float*)Cptr)[(size_t)r * Ndim + c] = v;
      }
    }
  }
}

// ---------------- K2: MFMA per-block max, pipelined (dbuf + reg prefetch) -----
__global__ __launch_bounds__(256) void kmax_mfma(
    const unsigned short* __restrict__ qkv, const unsigned short* __restrict__ Pbf,
    float* __restrict__ bmax)
{
  __shared__ unsigned short K_lds[2][64 * KVS];
  __shared__ float red[4];
  const int tid = threadIdx.x;
  const int w = tid >> 6, lane = tid & 63;
  const int lr = lane & 15, q = lane >> 4;
  const int bh = blockIdx.x, chunk = blockIdx.y;
  const int b = bh / H_, h = bh % H_;
  const int ms = w * 4;
  const int mc = (w == 3) ? 5 : 4;
  const int sn = 16 * w + (lane >> 2);
  const int sd0 = (lane & 3) * 16;
  const f32x4 fz = {0.f, 0.f, 0.f, 0.f};
  float mx = NEG_INF;

  bf16x8 pf0[5], pf1[5];
#pragma unroll
  for (int i = 0; i < 5; ++i) {
    const unsigned short* prow = Pbf + (size_t)((ms + i) * 16 + lr) * 64 + q * 8;
    pf0[i] = *(const bf16x8*)prow;
    pf1[i] = *(const bf16x8*)(prow + 32);
  }

  const unsigned short* kbase = qkv + (size_t)(b * N_TOK + chunk * 512 + sn) * TC_ + C_ + h * HD_ + sd0;
  const size_t gstep = (size_t)64 * TC_;

  int4 ka = *(const int4*)kbase;
  int4 kb = *(const int4*)(kbase + 8);
  *(int4*)&K_lds[0][sn * KVS + sd0] = ka;
  *(int4*)&K_lds[0][sn * KVS + sd0 + 8] = kb;
  asm volatile("s_waitcnt lgkmcnt(0)" ::: "memory");
  __builtin_amdgcn_s_barrier();

#pragma unroll 1
  for (int g = 0; g < 8; ++g) {
    const unsigned short* Kc = K_lds[g & 1];
    if (g < 7) {
      const unsigned short* kr = kbase + (size_t)(g + 1) * gstep;
      ka = *(const int4*)kr;
      kb = *(const int4*)(kr + 8);
    }
    __builtin_amdgcn_sched_barrier(0);
    bf16x8 bk[4][2];
#pragma unroll
    for (int nt = 0; nt < 4; ++nt) {
      bk[nt][0] = *(const bf16x8*)&Kc[(nt * 16 + lr) * KVS + q * 8];
      bk[nt][1] = *(const bf16x8*)&Kc[(nt * 16 + lr) * KVS + 32 + q * 8];
    }
#pragma unroll
    for (int i = 0; i < 5; ++i) {
      if (i >= mc) continue;
      const int m = (ms + i) * 16 + lr;
#pragma unroll
      for (int nt = 0; nt < 4; ++nt) {
        f32x4 s = fz;
        s = __builtin_amdgcn_mfma_f32_16x16x32_bf16(bk[nt][0], pf0[i], s, 0, 0, 0);
        s = __builtin_amdgcn_mfma_f32_16x16x32_bf16(bk[nt][1], pf1[i], s, 0, 0, 0);
        if (m < M_)
          mx = fmaxf(mx, fmaxf(fmaxf(s[0], s[1]), fmaxf(s[2], s[3])));
      }
    }
    if (g < 7) {
      __builtin_amdgcn_sched_barrier(0);
      unsigned short* Kn = (unsigned short*)K_lds[(g & 1) ^ 1];
      *(int4*)&Kn[sn * KVS + sd0] = ka;
      *(int4*)&Kn[sn * KVS + sd0 + 8] = kb;
      asm volatile("s_waitcnt lgkmcnt(0)" ::: "memory");
      __builtin_amdgcn_sched_barrier(0);
      __builtin_amdgcn_s_barrier();
      __builtin_amdgcn_sched_barrier(0);
    }
  }
#pragma unroll
  for (int off = 32; off >= 1; off >>= 1) mx = fmaxf(mx, __shfl_xor(mx, off));
  if (lane == 0) red[w] = mx;
  __syncthreads();
  if (tid == 0)
    bmax[chunk * BH_ + bh] = fmaxf(fmaxf(red[0], red[1]), fmaxf(red[2], red[3]));
}

__global__ __launch_bounds__(256) void kmax_reduce(
    const float* __restrict__ bmax, float* __restrict__ kmaxp, int n)
{
  __shared__ float red[4];
  float v = NEG_INF;
  for (int i = threadIdx.x; i < n; i += 256) v = fmaxf(v, bmax[i]);
#pragma unroll
  for (int off = 32; off >= 1; off >>= 1) v = fmaxf(v, __shfl_xor(v, off));
  if ((threadIdx.x & 63) == 0) red[threadIdx.x >> 6] = v;
  __syncthreads();
  if (threadIdx.x == 0)
    kmaxp[0] = DN * fmaxf(fmaxf(red[0], red[1]), fmaxf(red[2], red[3]));
}

// ---------------- K3: MFMA k-features -> partial kv^T, pipelined --------------
__global__ __launch_bounds__(256) void kv_partial_mfma(
    const unsigned short* __restrict__ qkv, const unsigned short* __restrict__ Pbf,
    const float* __restrict__ kmaxp,
    float* __restrict__ kvpart, float* __restrict__ ksumpart)
{
  __shared__ unsigned short K_lds[2][64 * KVS];
  __shared__ unsigned short Vt_lds[2][64 * KVS];
  __shared__ unsigned short k1_lds[272 * KVS];
  __shared__ float diag_lds[2][64];
  const int tid = threadIdx.x;
  const int w = tid >> 6, lane = tid & 63;
  const int lr = lane & 15, q = lane >> 4;
  const int bh = blockIdx.x, chunk = blockIdx.y;
  const int b = bh / H_, h = bh % H_;
  const float stab = kmaxp[0];
  const int ms = w * 4;
  const int mc = (w == 3) ? 5 : 4;
  const int sn = 16 * w + (lane >> 2);
  const int sd0 = (lane & 3) * 16;
  const f32x4 fz = {0.f, 0.f, 0.f, 0.f};

  f32x4 kvacc[5][4];
  float ksacc[5];
#pragma unroll
  for (int i = 0; i < 5; ++i) {
    ksacc[i] = 0.f;
#pragma unroll
    for (int dt = 0; dt < 4; ++dt) kvacc[i][dt] = fz;
  }

  bf16x8 pf0[5], pf1[5];
#pragma unroll
  for (int i = 0; i < 5; ++i) {
    const unsigned short* prow = Pbf + (size_t)((ms + i) * 16 + lr) * 64 + q * 8;
    pf0[i] = *(const bf16x8*)prow;
    pf1[i] = *(const bf16x8*)(prow + 32);
  }

  const unsigned short* kbase = qkv + (size_t)(b * N_TOK + chunk * 512 + sn) * TC_ + C_ + h * HD_ + sd0;
  const size_t gstep = (size_t)64 * TC_;

  auto write_buf = [&](int bsel, int4 wka, int4 wkb, int4 wva, int4 wvb) {
    *(int4*)&K_lds[bsel][sn * KVS + sd0] = wka;
    *(int4*)&K_lds[bsel][sn * KVS + sd0 + 8] = wkb;
    float sq = 0.f;
    const unsigned short* pk0 = (const unsigned short*)&wka;
#pragma unroll
    for (int j = 0; j < 8; ++j) { float f = bf2f(pk0[j]); sq = fmaf(f, f, sq); }
    const unsigned short* pk1 = (const unsigned short*)&wkb;
#pragma unroll
    for (int j = 0; j < 8; ++j) { float f = bf2f(pk1[j]); sq = fmaf(f, f, sq); }
    sq += __shfl_xor(sq, 1);
    sq += __shfl_xor(sq, 2);
    if ((lane & 3) == 0) diag_lds[bsel][sn] = 0.0625f * sq;
    const unsigned short* pv0 = (const unsigned short*)&wva;
    const unsigned short* pv1 = (const unsigned short*)&wvb;
#pragma unroll
    for (int j = 0; j < 8; ++j) Vt_lds[bsel][(sd0 + j) * KVS + sn] = pv0[j];
#pragma unroll
    for (int j = 0; j < 8; ++j) Vt_lds[bsel][(sd0 + 8 + j) * KVS + sn] = pv1[j];
  };

  int4 ka = *(const int4*)kbase;
  int4 kb = *(const int4*)(kbase + 8);
  int4 va = *(const int4*)(kbase + C_);
  int4 vb = *(const int4*)(kbase + C_ + 8);
  write_buf(0, ka, kb, va, vb);
  asm volatile("s_waitcnt lgkmcnt(0)" ::: "memory");
  __builtin_amdgcn_s_barrier();

#pragma unroll 1
  for (int g = 0; g < 8; ++g) {
    const int cur = g & 1;
    const unsigned short* Kc = K_lds[cur];
    const unsigned short* Vc = Vt_lds[cur];
    const float* Dc = diag_lds[cur];
    if (g < 7) {
      const unsigned short* kr = kbase + (size_t)(g + 1) * gstep;
      ka = *(const int4*)kr;
      kb = *(const int4*)(kr + 8);
      va = *(const int4*)(kr + C_);
      vb = *(const int4*)(kr + C_ + 8);
    }
    __builtin_amdgcn_sched_barrier(0);

    bf16x8 bk[4][2];
#pragma unroll
    for (int nt = 0; nt < 4; ++nt) {
      bk[nt][0] = *(const bf16x8*)&Kc[(nt * 16 + lr) * KVS + q * 8];
      bk[nt][1] = *(const bf16x8*)&Kc[(nt * 16 + lr) * KVS + 32 + q * 8];
    }

#pragma unroll
    for (int i = 0; i < 5; ++i) {
      if (i >= mc) continue;
      const int mt = ms + i;
      const int m = mt * 16 + lr;
      float loc = 0.f;
#pragma unroll
      for (int nt = 0; nt < 4; ++nt) {
        f32x4 s = fz;
        s = __builtin_amdgcn_mfma_f32_16x16x32_bf16(bk[nt][0], pf0[i], s, 0, 0, 0);
        s = __builtin_amdgcn_mfma_f32_16x16x32_bf16(bk[nt][1], pf1[i], s, 0, 0, 0);
        ushort4 uo;
        unsigned short* puo = (unsigned short*)&uo;
#pragma unroll
        for (int j = 0; j < 4; ++j) {
          const int nl = nt * 16 + q * 4 + j;
          float k1f = 0.f;
          if (m < M_) {
            float dash = DN * s[j];
            k1f = RATIO * (__expf(dash - Dc[nl] - stab) + FEPS);
          }
          loc += k1f;
          puo[j] = f2bf(k1f);
        }
        *(ushort4*)&k1_lds[(size_t)(mt * 16 + lr) * KVS + nt * 16 + q * 4] = uo;
      }
      ksacc[i] += loc;
    }
#pragma unroll
    for (int ks = 0; ks < 2; ++ks) {
      bf16x8 bv[4];
#pragma unroll
      for (int dt = 0; dt < 4; ++dt)
        bv[dt] = *(const bf16x8*)&Vc[(dt * 16 + lr) * KVS + ks * 32 + q * 8];
#pragma unroll
      for (int i = 0; i < 5; ++i) {
        if (i >= mc) continue;
        bf16x8 a1 = *(const bf16x8*)&k1_lds[(size_t)((ms + i) * 16 + lr) * KVS + ks * 32 + q * 8];
#pragma unroll
        for (int dt = 0; dt < 4; ++dt)
          kvacc[i][dt] = __builtin_amdgcn_mfma_f32_16x16x32_bf16(a1, bv[dt], kvacc[i][dt], 0, 0, 0);
      }
    }

    if (g < 7) {
      __builtin_amdgcn_sched_barrier(0);
      write_buf(cur ^ 1, ka, kb, va, vb);
      asm volatile("s_waitcnt lgkmcnt(0)" ::: "memory");
      __builtin_amdgcn_sched_barrier(0);
      __builtin_amdgcn_s_barrier();
      __builtin_amdgcn_sched_barrier(0);
    }
  }

  const size_t cb = (size_t)(chunk * BH_ + bh) * 64;
#pragma unroll
  for (int i = 0; i < 5; ++i) {
    if (i >= mc) continue;
    const int mt = ms + i;
#pragma unroll
    for (int dt = 0; dt < 4; ++dt) {
      float4 v4;
      v4.x = kvacc[i][dt][0]; v4.y = kvacc[i][dt][1];
      v4.z = kvacc[i][dt][2]; v4.w = kvacc[i][dt][3];
      *(float4*)&kvpart[(cb + dt * 16 + lr) * M2 + mt * 16 + q * 4] = v4;
    }
    float s = ksacc[i];
    s += __shfl_xor(s, 16);
    s += __shfl_xor(s, 32);
    if (lane < 16)
      ksumpart[(size_t)(chunk * BH_ + bh) * M2 + mt * 16 + lane] = s;
  }
}

// ---------------- K4: reduce partials -> kvt_g bf16 [bh][64][288], ksum_g f32 ----
__global__ __launch_bounds__(256) void kv_reduce2(
    const float* __restrict__ kvpart, const float* __restrict__ ksumpart,
    unsigned short* __restrict__ kvt_g, float* __restrict__ ksum_g)
{
  const int KVN = BH_ * 64 * M2;
  const int KSN = BH_ * M2;
  int idx = blockIdx.x * 256 + threadIdx.x;
  if (idx < KVN) {
    int m = idx % M2;
    float s = 0.f;
    if (m < M_) {
#pragma unroll
      for (int c = 0; c < 8; ++c) s += kvpart[(size_t)c * KVN + idx];
    }
    kvt_g[idx] = f2bf(s);
  } else if (idx < KVN + KSN) {
    int j = idx - KVN;
    int m = j % M2;
    float s = 0.f;
    if (m < M_) {
#pragma unroll
      for (int c = 0; c < 8; ++c) s += ksumpart[(size_t)c * KSN + j];
    }
    ksum_g[j] = s;
  }
}

// ---------------- K5: MFMA q-features + PV + normalize ----------------
__global__ __launch_bounds__(256) void attn_mfma(
    const unsigned short* __restrict__ qkv, const unsigned short* __restrict__ Pbf,
    const unsigned short* __restrict__ kvt_g, const float* __restrict__ ksum_g,
    unsigned short* __restrict__ attn)
{
  __shared__ unsigned short q1_lds[64 * MP];
  __shared__ unsigned short kvt_lds[64 * MP];
  __shared__ float ksum_lds[M2];
  __shared__ float z_lds[64];
  const int tid = threadIdx.x;
  const int bh = blockIdx.x, qt = blockIdx.y;
  const int b = bh / H_, h = bh % H_;
  const int n0 = qt * 64;
  const int w = tid >> 6, lane = tid & 63;
  const int lr = lane & 15, q = lane >> 4;

  {
    const unsigned short* src = kvt_g + (size_t)bh * 64 * M2;
#pragma unroll
    for (int i = 0; i < 9; ++i) {
      int chunk = i * 256 + tid;
      int r = chunk / 36, c = (chunk % 36) * 8;
      *(int4*)&kvt_lds[r * MP + c] = *(const int4*)(src + r * M2 + c);
    }
    if (tid < 72)
      *(float4*)&ksum_lds[tid * 4] = *(const float4*)(ksum_g + (size_t)bh * M2 + tid * 4);
    if (tid < 64) {
      const int4 z4 = {0, 0, 0, 0};
      *(int4*)&q1_lds[tid * MP + 272] = z4;
      *(int4*)&q1_lds[tid * MP + 280] = z4;
    }
  }
  __syncthreads();

  const unsigned short* qrow = qkv + (size_t)(b * N_TOK + n0 + w * 16 + lr) * TC_ + h * HD_;
  bf16x8 bq0 = *(const bf16x8*)(qrow + q * 8);
  bf16x8 bq1 = *(const bf16x8*)(qrow + q * 8 + 32);
  float sq = 0.f;
  {
    const unsigned short* p0 = (const unsigned short*)&bq0;
    const unsigned short* p1 = (const unsigned short*)&bq1;
#pragma unroll
    for (int j = 0; j < 8; ++j) { float f = bf2f(p0[j]); sq = fmaf(f, f, sq); }
#pragma unroll
    for (int j = 0; j < 8; ++j) { float f = bf2f(p1[j]); sq = fmaf(f, f, sq); }
  }
  sq += __shfl_xor(sq, 16);
  sq += __shfl_xor(sq, 32);
  const float diag = 0.0625f * sq;

  f32x4 sacc[17];
  const f32x4 fz = {0.f, 0.f, 0.f, 0.f};
#pragma unroll
  for (int mt = 0; mt < 17; ++mt) sacc[mt] = fz;
#pragma unroll
  for (int mt = 0; mt < 17; ++mt) {
    const unsigned short* prow = Pbf + (size_t)(mt * 16 + lr) * 64;
    bf16x8 ap0 = *(const bf16x8*)(prow + q * 8);
    bf16x8 ap1 = *(const bf16x8*)(prow + q * 8 + 32);
    sacc[mt] = __builtin_amdgcn_mfma_f32_16x16x32_bf16(ap0, bq0, sacc[mt], 0, 0, 0);
    sacc[mt] = __builtin_amdgcn_mfma_f32_16x16x32_bf16(ap1, bq1, sacc[mt], 0, 0, 0);
  }

  float mxr = NEG_INF;
#pragma unroll
  for (int mt = 0; mt < 17; ++mt) {
#pragma unroll
    for (int j = 0; j < 4; ++j) {
      int m = mt * 16 + q * 4 + j;
      if (m < M_) mxr = fmaxf(mxr, sacc[mt][j]);
    }
  }
  mxr = fmaxf(mxr, __shfl_xor(mxr, 16));
  mxr = fmaxf(mxr, __shfl_xor(mxr, 32));
  const float mxd = DN * mxr;

  float zp = 0.f;
#pragma unroll
  for (int mt = 0; mt < 17; ++mt) {
    ushort4 uo;
    unsigned short* puo = (unsigned short*)&uo;
#pragma unroll
    for (int j = 0; j < 4; ++j) {
      const int m = mt * 16 + q * 4 + j;
      float q1f = 0.f;
      if (m < M_) {
        float dash = DN * sacc[mt][j];
        q1f = RATIO * (__expf(dash - diag - mxd) + FEPS);
      }
      zp = fmaf(q1f, ksum_lds[m], zp);
      puo[j] = f2bf(q1f);
    }
    *(ushort4*)&q1_lds[(w * 16 + lr) * MP + mt * 16 + q * 4] = uo;
  }
  zp += __shfl_xor(zp, 16);
  zp += __shfl_xor(zp, 32);
  if (q == 0) z_lds[w * 16 + lr] = 1.0f / zp;

  f32x4 oacc[4];
#pragma unroll
  for (int dt = 0; dt < 4; ++dt) oacc[dt] = fz;
#pragma unroll
  for (int ks = 0; ks < 9; ++ks) {
    bf16x8 aq = *(const bf16x8*)&q1_lds[(w * 16 + lr) * MP + ks * 32 + q * 8];
#pragma unroll
    for (int dt = 0; dt < 4; ++dt) {
      bf16x8 bkv = *(const bf16x8*)&kvt_lds[(dt * 16 + lr) * MP + ks * 32 + q * 8];
      oacc[dt] = __builtin_amdgcn_mfma_f32_16x16x32_bf16(aq, bkv, oacc[dt], 0, 0, 0);
    }
  }

  float zz[4];
#pragma unroll
  for (int j = 0; j < 4; ++j) zz[j] = z_lds[w * 16 + q * 4 + j];
#pragma unroll
  for (int dt = 0; dt < 4; ++dt) {
#pragma unroll
    for (int j = 0; j < 4; ++j) {
      const int r = b * N_TOK + n0 + w * 16 + q * 4 + j;
      attn[(size_t)r * C_ + h * HD_ + dt * 16 + lr] = f2bf(oacc[dt][j] * zz[j]);
    }
  }
}

extern "C" void kernel_launch(void* const* d_in, const int* in_sizes, int n_in,
                              void* d_out, int out_size, void* d_ws, size_t ws_size,
                              hipStream_t stream) {
  const float* x     = (const float*)d_in[0];
  const float* Wqkv  = (const float*)d_in[1];
  const float* Wproj = (const float*)d_in[2];
  const float* bproj = (const float*)d_in[3];
  const float* P     = (const float*)d_in[4];
  float* out = (float*)d_out;
  float* ws = (float*)d_ws;

  // ws layout (f32 words), total ~54.23M words = 217 MiB
  unsigned short* qkv    = (unsigned short*)ws;                 // [0, 37748736)
  unsigned short* xb     = (unsigned short*)(ws + 37748736);    // 12,582,912 w
  float*          kvpart = ws + 37748736;                       // 14,155,776 w
  unsigned short* attn   = (unsigned short*)(ws + 37748736);    // 12,582,912 w
  float* ksumpart = ws + 51904512;                              // 221,184 w
  unsigned short* kvt_g  = (unsigned short*)(ws + 52125696);    // 884,736 w
  float* ksum_g   = ws + 53010432;                              // 27,648 w
  float* bmax     = ws + 53038080;                              // 3,072 w
  float* kmaxp    = ws + 53041152;                              // 64 w
  unsigned short* Pbf    = (unsigned short*)(ws + 53041216);    // 9,216 w
  unsigned short* Wqkvt  = (unsigned short*)(ws + 53050432);    // 884,736 w
  unsigned short* Wprojt = (unsigned short*)(ws + 53935168);    // 294,912 w

  cast_bf16<<<dim3(24576), 256, 0, stream>>>(x, xb, ROWS_ * C_);
  transpose_cast<<<dim3(72, 24), 256, 0, stream>>>(Wqkv, Wqkvt, C_, TC_);
  transpose_cast<<<dim3(24, 24), 256, 0, stream>>>(Wproj, Wprojt, C_, C_);
  cast_pbf<<<dim3(72), 256, 0, stream>>>(P, Pbf);

  gemm_pipe<18, 1, 0><<<dim3(2304), 512, 0, stream>>>(xb, Wqkvt, nullptr, qkv);
  kmax_mfma<<<dim3(96, 8), 256, 0, stream>>>(qkv, Pbf, bmax);
  kmax_reduce<<<dim3(1), 256, 0, stream>>>(bmax, kmaxp, 768);
  kv_partial_mfma<<<dim3(96, 8), 256, 0, stream>>>(qkv, Pbf, kmaxp, kvpart, ksumpart);
  kv_reduce2<<<dim3(7020), 256, 0, stream>>>(kvpart, ksumpart, kvt_g, ksum_g);
  attn_mfma<<<dim3(96, 64), 256, 0, stream>>>(qkv, Pbf, kvt_g, ksum_g, attn);
  gemm_pipe<6, 0, 1><<<dim3(768), 512, 0, stream>>>(attn, Wprojt, bproj, out);
}